// Round 6
// baseline (124.300 us; speedup 1.0000x reference)
//
#include <hip/hip_runtime.h>
#include <hip/hip_bf16.h>

typedef _Float16 f16;
typedef __attribute__((ext_vector_type(4))) _Float16 f16x4;
typedef __attribute__((ext_vector_type(8))) _Float16 f16x8;
typedef __attribute__((ext_vector_type(4))) float f32x4;

#define CD 256
#define ND 4096
#define GD 32
#define KVB 32          // keys per iteration

// async global->LDS, 16B per lane, lds dest must be wave-uniform base
__device__ __forceinline__ void gl_lds16(const f16* g, f16* l) {
    __builtin_amdgcn_global_load_lds(
        (const __attribute__((address_space(1))) unsigned int*)g,
        (__attribute__((address_space(3))) unsigned int*)l,
        16, 0, 0);
}

// ============================================================================
// Kernel 1: fused QKV projection.  p[b,o,n] = sum_c W[o,c] x[b,c,n] + bias[o]
// One block computes q,k,v for the same (o0,n0): x tile staged ONCE (3x less
// x traffic).  Q,K written TRANSPOSED [b][n][c] f16; V natural [b][c][n] f16.
// ============================================================================
__global__ __launch_bounds__(256)
void k_proj_qkv(const float* __restrict__ x,
                const float* __restrict__ Wq, const float* __restrict__ bq,
                const float* __restrict__ Wk, const float* __restrict__ bk,
                const float* __restrict__ Wv, const float* __restrict__ bv,
                f16* __restrict__ Qt, f16* __restrict__ Kt, f16* __restrict__ Vb)
{
    __shared__ f16 As[3][64][40];
    __shared__ f16 Bs[64][40];
    __shared__ f16 Ts[64][72];

    const int t  = threadIdx.x;
    const int n0 = blockIdx.x * 64;
    const int o0 = blockIdx.y * 64;
    const int bb = blockIdx.z;

    const float* Ws[3] = { Wq, Wk, Wv };
    const float* bs[3] = { bq, bk, bv };

    const int w  = t >> 6;
    const int l  = t & 63;
    const int lr = l & 15;
    const int lg = l >> 4;
    const int wo = (w >> 1) * 32;
    const int wn = (w & 1) * 32;

    const int sl = t & 63;
    const int k8 = (t >> 6) * 8;

    f32x4 acc[3][2][2] = {};

    for (int ck = 0; ck < CD; ck += 32) {
        __syncthreads();
#pragma unroll
        for (int p = 0; p < 3; ++p) {
            const float* s = Ws[p] + (size_t)(o0 + sl) * CD + ck + k8;
            f16x8 v;
#pragma unroll
            for (int u = 0; u < 8; ++u) v[u] = (f16)s[u];
            *(f16x8*)&As[p][sl][k8] = v;
        }
        {
            const float* s = x + ((size_t)bb * CD + ck + k8) * ND + n0 + sl;
            f16x8 v;
#pragma unroll
            for (int u = 0; u < 8; ++u) v[u] = (f16)s[(size_t)u * ND];
            *(f16x8*)&Bs[sl][k8] = v;
        }
        __syncthreads();
        f16x8 b0 = *(const f16x8*)&Bs[wn + lr][lg * 8];
        f16x8 b1 = *(const f16x8*)&Bs[wn + 16 + lr][lg * 8];
#pragma unroll
        for (int p = 0; p < 3; ++p) {
            f16x8 a0 = *(const f16x8*)&As[p][wo + lr][lg * 8];
            f16x8 a1 = *(const f16x8*)&As[p][wo + 16 + lr][lg * 8];
            acc[p][0][0] = __builtin_amdgcn_mfma_f32_16x16x32_f16(a0, b0, acc[p][0][0], 0, 0, 0);
            acc[p][0][1] = __builtin_amdgcn_mfma_f32_16x16x32_f16(a0, b1, acc[p][0][1], 0, 0, 0);
            acc[p][1][0] = __builtin_amdgcn_mfma_f32_16x16x32_f16(a1, b0, acc[p][1][0], 0, 0, 0);
            acc[p][1][1] = __builtin_amdgcn_mfma_f32_16x16x32_f16(a1, b1, acc[p][1][1], 0, 0, 0);
        }
    }

    // Q, K: transpose via Ts then coalesced [n][c] writes
#pragma unroll
    for (int p = 0; p < 2; ++p) {
        __syncthreads();
#pragma unroll
        for (int so = 0; so < 2; ++so)
#pragma unroll
            for (int r = 0; r < 4; ++r) {
                int orow  = wo + so * 16 + lg * 4 + r;
                float bv_ = bs[p][o0 + orow];
#pragma unroll
                for (int sn = 0; sn < 2; ++sn)
                    Ts[orow][wn + sn * 16 + lr] = (f16)(acc[p][so][sn][r] + bv_);
            }
        __syncthreads();
        f16* dst = (p == 0) ? Qt : Kt;
        int n  = t >> 2;
        int o8 = (t & 3) * 16;
        f16 tmp[16];
#pragma unroll
        for (int u = 0; u < 16; ++u) tmp[u] = Ts[o8 + u][n];
        f16* g = dst + ((size_t)bb * ND + n0 + n) * CD + o0 + o8;
        *(f16x8*)g       = *(f16x8*)&tmp[0];
        *(f16x8*)(g + 8) = *(f16x8*)&tmp[8];
    }
    // V: direct [c][n] writes
#pragma unroll
    for (int so = 0; so < 2; ++so)
#pragma unroll
        for (int r = 0; r < 4; ++r) {
            int orow  = wo + so * 16 + lg * 4 + r;
            float bv_ = bv[o0 + orow];
#pragma unroll
            for (int sn = 0; sn < 2; ++sn) {
                int ncol = wn + sn * 16 + lr;
                Vb[((size_t)bb * CD + o0 + orow) * ND + n0 + ncol] =
                    (f16)(acc[2][so][sn][r] + bv_);
            }
        }
}

// ============================================================================
// Kernel 2: flash attention, split-K (template KSN).
// 8 waves x 16 queries (QBLK=128) sharing K/V tiles -> 74.75 KB LDS ->
// 2 blocks/CU = 4 waves/SIMD.  KVB=32 keys/iter, double-buffered.
// SWAPPED QK^T: S = mfma(A=K, B=Q) -> lane-local softmax (2 shfls).
// Writes unnormalized O partial (f16) + per-row (m,l) (f32).
// ============================================================================
template<int KSN>
__global__ __launch_bounds__(512, 4)
void k_attn(const f16* __restrict__ Qt, const f16* __restrict__ Kt,
            const f16* __restrict__ Vb, f16* __restrict__ Op,
            float* __restrict__ ml)
{
    __shared__ f16 Ks[2][32 * 256];   // [buf][row][chunk16B ^ (row&7)]      2x16 KB
    __shared__ f16 Vs[2][256 * 32];   // [buf][c][chunk16B ^ ((c>>1)&3)]     2x16 KB
    __shared__ f16 Pl[8][16][36];     // per-wave P [q_local][m]             9 KB

    const int t  = threadIdx.x;
    const int w  = t >> 6;           // 0..7
    const int l  = t & 63;
    const int lr = l & 15;
    const int lg = l >> 4;
    const int ks = blockIdx.y;
    const int bb = blockIdx.z;
    const int q0 = blockIdx.x * 128 + w * 16;

    // Q fragments in registers (16 q rows = lr)
    f16x8 qf[8];
#pragma unroll
    for (int kc = 0; kc < 8; ++kc)
        qf[kc] = *(const f16x8*)(Qt + ((size_t)bb * ND + q0 + lr) * CD + kc * 32 + lg * 8);

    f32x4 oacc[16] = {};
    float row_m = -3.0e38f, row_l = 0.f;

    const int kv0 = ks * (ND / KSN);
    const f16* ktb = Kt + (size_t)bb * ND * CD;
    const f16* vbb = Vb + (size_t)bb * CD * ND;

    // per-lane loop-invariant staging offsets (elements); 2 chunks each of K,V
    int koff[2], voff[2];
#pragma unroll
    for (int j = 0; j < 2; ++j) {
        int cidx = (w * 2 + j) * 64 + l;          // 0..1023 16B-chunks
        int krow = cidx >> 5;                      // 32 chunks per K row
        int kch  = (cidx & 31) ^ (krow & 7);
        koff[j]  = krow * CD + kch * 8;
        int vc   = cidx >> 2;                      // 4 chunks per V row
        int vu   = (cidx & 3) ^ ((vc >> 1) & 3);
        voff[j]  = vc * ND + vu * 8;
    }

    auto stage = [&](int m0, int bi) {
#pragma unroll
        for (int j = 0; j < 2; ++j)
            gl_lds16(ktb + (size_t)m0 * CD + koff[j], &Ks[bi][(w * 2 + j) * 512]);
#pragma unroll
        for (int j = 0; j < 2; ++j)
            gl_lds16(vbb + m0 + voff[j], &Vs[bi][(w * 2 + j) * 512]);
    };

    stage(kv0, 0);
    __syncthreads();    // drains vmcnt; tile 0 resident

    const int NIT = (ND / KSN) / KVB;
    for (int it = 0; it < NIT; ++it) {
        const int bi = it & 1;
        if (it + 1 < NIT) stage(kv0 + (it + 1) * KVB, bi ^ 1);

        // ---- scores S[m][q]: 2 m-subtiles ----
        f32x4 s0 = {}, s1 = {};
        __builtin_amdgcn_s_setprio(1);
#pragma unroll
        for (int kc = 0; kc < 8; ++kc) {
            int chs = ((kc * 4 + lg) ^ (lr & 7)) * 8;
            f16x8 k0 = *(const f16x8*)&Ks[bi][(lr) * 256 + chs];
            f16x8 k1 = *(const f16x8*)&Ks[bi][(16 + lr) * 256 + chs];
            s0 = __builtin_amdgcn_mfma_f32_16x16x32_f16(k0, qf[kc], s0, 0, 0, 0);
            s1 = __builtin_amdgcn_mfma_f32_16x16x32_f16(k1, qf[kc], s1, 0, 0, 0);
        }
        __builtin_amdgcn_s_setprio(0);

        // ---- lane-local online softmax: lane (lr,lg) holds S[m=sub*16+lg*4+r][q=lr]
        {
            float pm = fmaxf(
                fmaxf(fmaxf(s0[0], s0[1]), fmaxf(s0[2], s0[3])),
                fmaxf(fmaxf(s1[0], s1[1]), fmaxf(s1[2], s1[3])));
            pm = fmaxf(pm, __shfl_xor(pm, 16));
            pm = fmaxf(pm, __shfl_xor(pm, 32));
            float nm = fmaxf(row_m, pm);
            float sc = __expf(row_m - nm);
            float p0 = __expf(s0[0] - nm);
            float p1 = __expf(s0[1] - nm);
            float p2 = __expf(s0[2] - nm);
            float p3 = __expf(s0[3] - nm);
            float p4 = __expf(s1[0] - nm);
            float p5 = __expf(s1[1] - nm);
            float p6 = __expf(s1[2] - nm);
            float p7 = __expf(s1[3] - nm);
            float ps = ((p0 + p1) + (p2 + p3)) + ((p4 + p5) + (p6 + p7));
            ps += __shfl_xor(ps, 16);
            ps += __shfl_xor(ps, 32);
            bool chg = nm > row_m;
            row_l = row_l * sc + ps;
            row_m = nm;
            if (__any(chg)) {   // skip exact-1 rescale when max unchanged
#pragma unroll
                for (int ct = 0; ct < 16; ++ct) {
                    oacc[ct][0] *= sc; oacc[ct][1] *= sc;
                    oacc[ct][2] *= sc; oacc[ct][3] *= sc;
                }
            }
            f16x4 pk0 = { (f16)p0, (f16)p1, (f16)p2, (f16)p3 };
            f16x4 pk1 = { (f16)p4, (f16)p5, (f16)p6, (f16)p7 };
            *(f16x4*)&Pl[w][lr][lg * 4]      = pk0;
            *(f16x4*)&Pl[w][lr][16 + lg * 4] = pk1;
        }

        // ---- PV: O[c][q] += V[c][m] * P[m][q] ----
        f16x8 pf = *(const f16x8*)&Pl[w][lr][lg * 8];
        __builtin_amdgcn_s_setprio(1);
#pragma unroll
        for (int ct = 0; ct < 16; ++ct) {
            f16x8 vf = *(const f16x8*)&Vs[bi][(ct * 16 + lr) * 32 + ((lg ^ ((lr >> 1) & 3))) * 8];
            oacc[ct] = __builtin_amdgcn_mfma_f32_16x16x32_f16(vf, pf, oacc[ct], 0, 0, 0);
        }
        __builtin_amdgcn_s_setprio(0);
        __syncthreads();   // drains stage(it+1); frees buffers for next iter
    }

    // ---- write unnormalized partial + (m,l) ----
#pragma unroll
    for (int ct = 0; ct < 16; ++ct)
#pragma unroll
        for (int r = 0; r < 4; ++r) {
            int cch = ct * 16 + lg * 4 + r;
            Op[(((size_t)ks * 2 + bb) * CD + cch) * ND + q0 + lr] = (f16)oacc[ct][r];
        }
    if (lg == 0) {
        int n = q0 + lr;
        ml[((ks * 2 + bb) * 2 + 0) * ND + n] = row_m;
        ml[((ks * 2 + bb) * 2 + 1) * ND + n] = row_l;
    }
}

// ============================================================================
// Kernel 2b-i: per-n combine weights  wq[ks][b][n] = exp(m-M)/L
// ============================================================================
template<int KSN>
__global__ __launch_bounds__(256)
void k_ml(const float* __restrict__ ml, float* __restrict__ wq)
{
    int i = blockIdx.x * 256 + threadIdx.x;   // i over B*ND
    int b = i / ND, n = i % ND;
    float m[KSN], lv[KSN];
#pragma unroll
    for (int ks = 0; ks < KSN; ++ks) {
        m[ks]  = ml[((ks * 2 + b) * 2 + 0) * ND + n];
        lv[ks] = ml[((ks * 2 + b) * 2 + 1) * ND + n];
    }
    float M = m[0];
#pragma unroll
    for (int ks = 1; ks < KSN; ++ks) M = fmaxf(M, m[ks]);
    float wgt[KSN], L = 0.f;
#pragma unroll
    for (int ks = 0; ks < KSN; ++ks) { wgt[ks] = __expf(m[ks] - M); L += wgt[ks] * lv[ks]; }
    float inv = 1.0f / L;
#pragma unroll
    for (int ks = 0; ks < KSN; ++ks)
        wq[(ks * 2 + b) * ND + n] = wgt[ks] * inv;
}

// ============================================================================
// Kernel 2b-ii: combine split-K partials -> Hb[b][c][n] f16 (vectorized)
// ============================================================================
template<int KSN>
__global__ __launch_bounds__(256)
void k_comb(const f16* __restrict__ Op, const float* __restrict__ wq,
            f16* __restrict__ Hb)
{
    size_t i = (size_t)blockIdx.x * 256 + threadIdx.x;   // one f16x8 each
    int n0 = (int)(i % (ND / 8)) * 8;
    int c  = (int)((i / (ND / 8)) % CD);
    int b  = (int)(i / ((size_t)CD * (ND / 8)));

    float acc[8] = {};
#pragma unroll
    for (int ks = 0; ks < KSN; ++ks) {
        f16x8 o = *(const f16x8*)(Op + (((size_t)ks * 2 + b) * CD + c) * ND + n0);
        const float* wp = wq + (ks * 2 + b) * ND + n0;
        float4 w0 = *(const float4*)wp;
        float4 w1 = *(const float4*)(wp + 4);
        acc[0] += w0.x * (float)o[0]; acc[1] += w0.y * (float)o[1];
        acc[2] += w0.z * (float)o[2]; acc[3] += w0.w * (float)o[3];
        acc[4] += w1.x * (float)o[4]; acc[5] += w1.y * (float)o[5];
        acc[6] += w1.z * (float)o[6]; acc[7] += w1.w * (float)o[7];
    }
    f16x8 h;
#pragma unroll
    for (int u = 0; u < 8; ++u) h[u] = (f16)acc[u];
    *(f16x8*)(Hb + ((size_t)b * CD + c) * ND + n0) = h;
}

// ============================================================================
// Kernel 3: output projection + residual.  Y = Wo@H + bo + x  (f32 out)
// ============================================================================
__global__ __launch_bounds__(256)
void k_proj_o(const f16* __restrict__ Hb, const float* __restrict__ Wo,
              const float* __restrict__ bo, const float* __restrict__ x,
              float* __restrict__ Y)
{
    __shared__ f16 As[64][40];
    __shared__ f16 Bs[64][40];

    const int t  = threadIdx.x;
    const int n0 = blockIdx.x * 64;
    const int o0 = blockIdx.y * 64;
    const int bb = blockIdx.z;

    const int w  = t >> 6;
    const int l  = t & 63;
    const int lr = l & 15;
    const int lg = l >> 4;
    const int wo = (w >> 1) * 32;
    const int wn = (w & 1) * 32;

    const int sl = t & 63;
    const int k8 = (t >> 6) * 8;

    f32x4 acc[2][2] = {};

    for (int ck = 0; ck < CD; ck += 32) {
        __syncthreads();
        {
            const float* s = Wo + (size_t)(o0 + sl) * CD + ck + k8;
            f16x8 v;
#pragma unroll
            for (int u = 0; u < 8; ++u) v[u] = (f16)s[u];
            *(f16x8*)&As[sl][k8] = v;
        }
        {
            const f16* s = Hb + ((size_t)bb * CD + ck + k8) * ND + n0 + sl;
            f16x8 v;
#pragma unroll
            for (int u = 0; u < 8; ++u) v[u] = s[(size_t)u * ND];
            *(f16x8*)&Bs[sl][k8] = v;
        }
        __syncthreads();
        f16x8 a0 = *(const f16x8*)&As[wo + lr][lg * 8];
        f16x8 a1 = *(const f16x8*)&As[wo + 16 + lr][lg * 8];
        f16x8 b0 = *(const f16x8*)&Bs[wn + lr][lg * 8];
        f16x8 b1 = *(const f16x8*)&Bs[wn + 16 + lr][lg * 8];
        acc[0][0] = __builtin_amdgcn_mfma_f32_16x16x32_f16(a0, b0, acc[0][0], 0, 0, 0);
        acc[0][1] = __builtin_amdgcn_mfma_f32_16x16x32_f16(a0, b1, acc[0][1], 0, 0, 0);
        acc[1][0] = __builtin_amdgcn_mfma_f32_16x16x32_f16(a1, b0, acc[1][0], 0, 0, 0);
        acc[1][1] = __builtin_amdgcn_mfma_f32_16x16x32_f16(a1, b1, acc[1][1], 0, 0, 0);
    }

#pragma unroll
    for (int so = 0; so < 2; ++so)
#pragma unroll
        for (int r = 0; r < 4; ++r) {
            int orow  = wo + so * 16 + lg * 4 + r;
            float bv_ = bo[o0 + orow];
#pragma unroll
            for (int sn = 0; sn < 2; ++sn) {
                int ncol   = wn + sn * 16 + lr;
                size_t idx = ((size_t)bb * CD + o0 + orow) * ND + n0 + ncol;
                Y[idx] = acc[so][sn][r] + bv_ + x[idx];
            }
        }
}

// ============================================================================
// Kernel 4: per-(batch,group) mean/rstd
// ============================================================================
__global__ __launch_bounds__(256)
void k_stats(const float* __restrict__ Y, float* __restrict__ stats)
{
    const int g = blockIdx.x, b = blockIdx.y;
    const float* base = Y + ((size_t)b * CD + g * 8) * ND;
    float s = 0.f, s2 = 0.f;
    for (int i = threadIdx.x; i < (8 * ND) / 4; i += 256) {
        float4 v = ((const float4*)base)[i];
        s  += v.x + v.y + v.z + v.w;
        s2 += v.x * v.x + v.y * v.y + v.z * v.z + v.w * v.w;
    }
#pragma unroll
    for (int m = 1; m < 64; m <<= 1) {
        s  += __shfl_xor(s, m);
        s2 += __shfl_xor(s2, m);
    }
    __shared__ float red[8];
    if ((threadIdx.x & 63) == 0) {
        red[(threadIdx.x >> 6) * 2]     = s;
        red[(threadIdx.x >> 6) * 2 + 1] = s2;
    }
    __syncthreads();
    if (threadIdx.x == 0) {
        float S  = red[0] + red[2] + red[4] + red[6];
        float S2 = red[1] + red[3] + red[5] + red[7];
        float mean = S / 32768.f;
        float var  = S2 / 32768.f - mean * mean;
        stats[(b * GD + g) * 2]     = mean;
        stats[(b * GD + g) * 2 + 1] = rsqrtf(var + 1e-5f);
    }
}

// ============================================================================
// Kernel 5: normalize + affine + SiLU, f32 out
// ============================================================================
__global__ __launch_bounds__(256)
void k_norm_silu(const float* __restrict__ Y, const float* __restrict__ stats,
                 const float* __restrict__ gamma, const float* __restrict__ beta,
                 float* __restrict__ out)
{
    size_t i4 = (size_t)blockIdx.x * 256 + threadIdx.x;
    int c = (int)((i4 / (ND / 4)) % CD);
    int b = (int)(i4 / ((size_t)CD * (ND / 4)));
    float mean = stats[(b * GD + c / 8) * 2];
    float rstd = stats[(b * GD + c / 8) * 2 + 1];
    float ga = gamma[c], be = beta[c];
    float4 v = ((const float4*)Y)[i4];
    float in[4] = { v.x, v.y, v.z, v.w };
    float ob[4];
#pragma unroll
    for (int u = 0; u < 4; ++u) {
        float yn = (in[u] - mean) * rstd * ga + be;
        float sg = 1.0f / (1.0f + __expf(-yn));
        ob[u] = yn * sg;
    }
    *(float4*)(out + i4 * 4) = *(float4*)ob;
}

// ============================================================================
extern "C" void kernel_launch(void* const* d_in, const int* in_sizes, int n_in,
                              void* d_out, int out_size, void* d_ws, size_t ws_size,
                              hipStream_t stream)
{
    const float* x     = (const float*)d_in[0];
    const float* Wq    = (const float*)d_in[1];
    const float* bq    = (const float*)d_in[2];
    const float* Wk    = (const float*)d_in[3];
    const float* bk    = (const float*)d_in[4];
    const float* Wv    = (const float*)d_in[5];
    const float* bv    = (const float*)d_in[6];
    const float* Wo    = (const float*)d_in[7];
    const float* bo    = (const float*)d_in[8];
    const float* gamma = (const float*)d_in[9];
    const float* beta  = (const float*)d_in[10];

    char* ws = (char*)d_ws;
    f16* Qt = (f16*)(ws);                    //  0..4 MiB   [B][N][C]
    f16* Kt = (f16*)(ws + (4u << 20));       //  4..8 MiB   [B][N][C]
    f16* Vb = (f16*)(ws + (8u << 20));       //  8..12 MiB  [B][C][N]
    f16* Hb = (f16*)(ws + (12u << 20));      // 12..16 MiB  [B][C][N]
    f16* Op = (f16*)(ws + (16u << 20));      // 16.. MiB    [KSN][B][C][N]
    float* Y = (float*)(ws + (16u << 20));   // reuses Op region after combine

    const bool big = ws_size >= (50ull << 20);

    k_proj_qkv<<<dim3(64, 4, 2), 256, 0, stream>>>(x, Wq, bq, Wk, bk, Wv, bv, Qt, Kt, Vb);

    if (big) {
        constexpr int KSN = 8;
        float* ml    = (float*)(ws + (48u << 20));                // 512 KB
        float* wq    = (float*)(ws + (48u << 20) + (768u << 10)); // 256 KB
        float* stats = (float*)(ws + (49u << 20) + (512u << 10));
        k_attn<KSN><<<dim3(32, KSN, 2), 512, 0, stream>>>(Qt, Kt, Vb, Op, ml);
        k_ml<KSN><<<dim3((2 * ND) / 256), 256, 0, stream>>>(ml, wq);
        k_comb<KSN><<<dim3((2 * CD * ND / 8) / 256), 256, 0, stream>>>(Op, wq, Hb);
        k_proj_o<<<dim3(64, 4, 2), 256, 0, stream>>>(Hb, Wo, bo, x, Y);
        k_stats<<<dim3(32, 2), 256, 0, stream>>>(Y, stats);
        k_norm_silu<<<2048, 256, 0, stream>>>(Y, stats, gamma, beta, (float*)d_out);
    } else {
        constexpr int KSN = 4;
        float* ml    = (float*)(ws + (32u << 20));                // 256 KB
        float* wq    = (float*)(ws + (32u << 20) + (512u << 10)); // 128 KB
        float* stats = (float*)(ws + (33u << 20));
        k_attn<KSN><<<dim3(32, KSN, 2), 512, 0, stream>>>(Qt, Kt, Vb, Op, ml);
        k_ml<KSN><<<dim3((2 * ND) / 256), 256, 0, stream>>>(ml, wq);
        k_comb<KSN><<<dim3((2 * CD * ND / 8) / 256), 256, 0, stream>>>(Op, wq, Hb);
        k_proj_o<<<dim3(64, 4, 2), 256, 0, stream>>>(Hb, Wo, bo, x, Y);
        k_stats<<<dim3(32, 2), 256, 0, stream>>>(Y, stats);
        k_norm_silu<<<2048, 256, 0, stream>>>(Y, stats, gamma, beta, (float*)d_out);
    }
}

// Round 7
// 121.164 us; speedup vs baseline: 1.0259x; 1.0259x over previous
//
#include <hip/hip_runtime.h>
#include <hip/hip_bf16.h>

typedef _Float16 f16;
typedef __attribute__((ext_vector_type(4))) _Float16 f16x4;
typedef __attribute__((ext_vector_type(8))) _Float16 f16x8;
typedef __attribute__((ext_vector_type(4))) float f32x4;

#define CD 256
#define ND 4096
#define GD 32
#define KVB 32          // keys per iteration

// async global->LDS, 16B per lane, lds dest must be wave-uniform base
__device__ __forceinline__ void gl_lds16(const f16* g, f16* l) {
    __builtin_amdgcn_global_load_lds(
        (const __attribute__((address_space(1))) unsigned int*)g,
        (__attribute__((address_space(3))) unsigned int*)l,
        16, 0, 0);
}

// ============================================================================
// Kernel 1: fused QKV projection.  p[b,o,n] = sum_c W[o,c] x[b,c,n] + bias[o]
// Q,K written TRANSPOSED [b][n][c] f16; V natural [b][c][n] f16.
// ============================================================================
__global__ __launch_bounds__(256)
void k_proj_qkv(const float* __restrict__ x,
                const float* __restrict__ Wq, const float* __restrict__ bq,
                const float* __restrict__ Wk, const float* __restrict__ bk,
                const float* __restrict__ Wv, const float* __restrict__ bv,
                f16* __restrict__ Qt, f16* __restrict__ Kt, f16* __restrict__ Vb)
{
    __shared__ f16 As[3][64][40];
    __shared__ f16 Bs[64][40];
    __shared__ f16 Ts[64][72];

    const int t  = threadIdx.x;
    const int n0 = blockIdx.x * 64;
    const int o0 = blockIdx.y * 64;
    const int bb = blockIdx.z;

    const float* Ws[3] = { Wq, Wk, Wv };
    const float* bs[3] = { bq, bk, bv };

    const int w  = t >> 6;
    const int l  = t & 63;
    const int lr = l & 15;
    const int lg = l >> 4;
    const int wo = (w >> 1) * 32;
    const int wn = (w & 1) * 32;

    const int sl = t & 63;
    const int k8 = (t >> 6) * 8;

    f32x4 acc[3][2][2] = {};

    for (int ck = 0; ck < CD; ck += 32) {
        __syncthreads();
#pragma unroll
        for (int p = 0; p < 3; ++p) {
            const float* s = Ws[p] + (size_t)(o0 + sl) * CD + ck + k8;
            f16x8 v;
#pragma unroll
            for (int u = 0; u < 8; ++u) v[u] = (f16)s[u];
            *(f16x8*)&As[p][sl][k8] = v;
        }
        {
            const float* s = x + ((size_t)bb * CD + ck + k8) * ND + n0 + sl;
            f16x8 v;
#pragma unroll
            for (int u = 0; u < 8; ++u) v[u] = (f16)s[(size_t)u * ND];
            *(f16x8*)&Bs[sl][k8] = v;
        }
        __syncthreads();
        f16x8 b0 = *(const f16x8*)&Bs[wn + lr][lg * 8];
        f16x8 b1 = *(const f16x8*)&Bs[wn + 16 + lr][lg * 8];
#pragma unroll
        for (int p = 0; p < 3; ++p) {
            f16x8 a0 = *(const f16x8*)&As[p][wo + lr][lg * 8];
            f16x8 a1 = *(const f16x8*)&As[p][wo + 16 + lr][lg * 8];
            acc[p][0][0] = __builtin_amdgcn_mfma_f32_16x16x32_f16(a0, b0, acc[p][0][0], 0, 0, 0);
            acc[p][0][1] = __builtin_amdgcn_mfma_f32_16x16x32_f16(a0, b1, acc[p][0][1], 0, 0, 0);
            acc[p][1][0] = __builtin_amdgcn_mfma_f32_16x16x32_f16(a1, b0, acc[p][1][0], 0, 0, 0);
            acc[p][1][1] = __builtin_amdgcn_mfma_f32_16x16x32_f16(a1, b1, acc[p][1][1], 0, 0, 0);
        }
    }

    // Q, K: transpose via Ts then coalesced [n][c] writes
#pragma unroll
    for (int p = 0; p < 2; ++p) {
        __syncthreads();
#pragma unroll
        for (int so = 0; so < 2; ++so)
#pragma unroll
            for (int r = 0; r < 4; ++r) {
                int orow  = wo + so * 16 + lg * 4 + r;
                float bv_ = bs[p][o0 + orow];
#pragma unroll
                for (int sn = 0; sn < 2; ++sn)
                    Ts[orow][wn + sn * 16 + lr] = (f16)(acc[p][so][sn][r] + bv_);
            }
        __syncthreads();
        f16* dst = (p == 0) ? Qt : Kt;
        int n  = t >> 2;
        int o8 = (t & 3) * 16;
        f16 tmp[16];
#pragma unroll
        for (int u = 0; u < 16; ++u) tmp[u] = Ts[o8 + u][n];
        f16* g = dst + ((size_t)bb * ND + n0 + n) * CD + o0 + o8;
        *(f16x8*)g       = *(f16x8*)&tmp[0];
        *(f16x8*)(g + 8) = *(f16x8*)&tmp[8];
    }
    // V: direct [c][n] writes
#pragma unroll
    for (int so = 0; so < 2; ++so)
#pragma unroll
        for (int r = 0; r < 4; ++r) {
            int orow  = wo + so * 16 + lg * 4 + r;
            float bv_ = bv[o0 + orow];
#pragma unroll
            for (int sn = 0; sn < 2; ++sn) {
                int ncol = wn + sn * 16 + lr;
                Vb[((size_t)bb * CD + o0 + orow) * ND + n0 + ncol] =
                    (f16)(acc[2][so][sn][r] + bv_);
            }
        }
}

// ============================================================================
// Kernel 2: flash attention, split-K (template KSN).
// 4 waves x 32 queries (QBLK=128).  KVB=32 keys/iter, double-buffered LDS,
// 2 blocks/CU.  SWAPPED QK^T: lane-local softmax.  Defer-max THR=5.
// XCD-pinned flat grid: bid&7 = (ks&3)*2 + bb  -> per-XCD working set
// (2 K/V slices 1MB + one batch Q 2MB) fits the 4MB XCD L2.
// ============================================================================
template<int KSN>
__global__ __launch_bounds__(256, 2)
void k_attn(const f16* __restrict__ Qt, const f16* __restrict__ Kt,
            const f16* __restrict__ Vb, f16* __restrict__ Op,
            float* __restrict__ ml)
{
    __shared__ f16 Ks[2][32 * 256];   // [buf][row][chunk16B ^ (row&7)]  2x16 KB
    __shared__ f16 Vs[2][256 * 32];   // [buf][c][chunk16B ^ ((c>>1)&3)] 2x16 KB
    __shared__ f16 Pl[4][32][40];     // per-wave P [q_local][m]

    const int t  = threadIdx.x;
    const int w  = t >> 6;           // 0..3
    const int l  = t & 63;
    const int lr = l & 15;
    const int lg = l >> 4;

    // ---- XCD-pinned decode ----
    const int bid = blockIdx.x;
    int bb, ks, qi;
    if constexpr (KSN == 8) {
        int xcd = bid & 7;
        bb = xcd & 1;
        ks = (xcd >> 1) | ((bid >> 8) << 2);
        qi = (bid >> 3) & 31;
    } else {   // KSN == 4
        bb = bid & 1;
        ks = (bid >> 1) & 3;
        qi = bid >> 3;
    }
    const int q0 = qi * 128 + w * 32;

    // Q fragments in registers: 2 q-subgroups x 8 k-chunks
    f16x8 qf[2][8];
#pragma unroll
    for (int qs = 0; qs < 2; ++qs)
#pragma unroll
        for (int kc = 0; kc < 8; ++kc)
            qf[qs][kc] = *(const f16x8*)(Qt + ((size_t)bb * ND + q0 + qs * 16 + lr) * CD + kc * 32 + lg * 8);

    f32x4 oacc[2][16] = {};
    float row_m[2] = { -3.0e38f, -3.0e38f };
    float row_l[2] = { 0.f, 0.f };

    const int kv0 = ks * (ND / KSN);
    const f16* ktb = Kt + (size_t)bb * ND * CD;
    const f16* vbb = Vb + (size_t)bb * CD * ND;

    // per-lane loop-invariant staging offsets (elements)
    int koff[4], voff[4];
#pragma unroll
    for (int j = 0; j < 4; ++j) {
        int v   = (w * 4 + j) * 64 + l;
        int row = v >> 5;
        int ch  = (v & 31) ^ (row & 7);
        koff[j] = row * CD + ch * 8;
        int c   = v >> 2;
        int u   = (v & 3) ^ ((c >> 1) & 3);
        voff[j] = c * ND + u * 8;
    }

    auto stage = [&](int m0, int bi) {
#pragma unroll
        for (int j = 0; j < 4; ++j)
            gl_lds16(ktb + (size_t)m0 * CD + koff[j], &Ks[bi][(w * 4 + j) * 512]);
#pragma unroll
        for (int j = 0; j < 4; ++j)
            gl_lds16(vbb + m0 + voff[j], &Vs[bi][(w * 4 + j) * 512]);
    };

    stage(kv0, 0);
    __syncthreads();    // drains vmcnt; tile 0 resident

    const int NIT = (ND / KSN) / KVB;
    for (int it = 0; it < NIT; ++it) {
        const int bi = it & 1;
        if (it + 1 < NIT) stage(kv0 + (it + 1) * KVB, bi ^ 1);

        // ---- scores S[m][q]: 2 m-subtiles x 2 q-subgroups ----
        f32x4 s[2][2] = {};
        __builtin_amdgcn_s_setprio(1);
#pragma unroll
        for (int kc = 0; kc < 8; ++kc) {
            int chs = ((kc * 4 + lg) ^ (lr & 7)) * 8;
            f16x8 k0 = *(const f16x8*)&Ks[bi][(lr) * 256 + chs];
            f16x8 k1 = *(const f16x8*)&Ks[bi][(16 + lr) * 256 + chs];
            s[0][0] = __builtin_amdgcn_mfma_f32_16x16x32_f16(k0, qf[0][kc], s[0][0], 0, 0, 0);
            s[1][0] = __builtin_amdgcn_mfma_f32_16x16x32_f16(k1, qf[0][kc], s[1][0], 0, 0, 0);
            s[0][1] = __builtin_amdgcn_mfma_f32_16x16x32_f16(k0, qf[1][kc], s[0][1], 0, 0, 0);
            s[1][1] = __builtin_amdgcn_mfma_f32_16x16x32_f16(k1, qf[1][kc], s[1][1], 0, 0, 0);
        }
        __builtin_amdgcn_s_setprio(0);

        // ---- lane-local online softmax per q-subgroup (defer-max THR=5) ----
#pragma unroll
        for (int qs = 0; qs < 2; ++qs) {
            float pm = fmaxf(
                fmaxf(fmaxf(s[0][qs][0], s[0][qs][1]), fmaxf(s[0][qs][2], s[0][qs][3])),
                fmaxf(fmaxf(s[1][qs][0], s[1][qs][1]), fmaxf(s[1][qs][2], s[1][qs][3])));
            pm = fmaxf(pm, __shfl_xor(pm, 16));
            pm = fmaxf(pm, __shfl_xor(pm, 32));
            bool need = (pm > row_m[qs] + 5.0f);   // defer small max growth
            float nm  = need ? pm : row_m[qs];
            float p0 = __expf(s[0][qs][0] - nm);
            float p1 = __expf(s[0][qs][1] - nm);
            float p2 = __expf(s[0][qs][2] - nm);
            float p3 = __expf(s[0][qs][3] - nm);
            float p4 = __expf(s[1][qs][0] - nm);
            float p5 = __expf(s[1][qs][1] - nm);
            float p6 = __expf(s[1][qs][2] - nm);
            float p7 = __expf(s[1][qs][3] - nm);
            float ps = ((p0 + p1) + (p2 + p3)) + ((p4 + p5) + (p6 + p7));
            ps += __shfl_xor(ps, 16);
            ps += __shfl_xor(ps, 32);
            if (__any(need)) {
                float sc = __expf(row_m[qs] - nm);   // == 1 for lanes w/o change
                row_l[qs] = row_l[qs] * sc + ps;
#pragma unroll
                for (int ct = 0; ct < 16; ++ct) {
                    oacc[qs][ct][0] *= sc; oacc[qs][ct][1] *= sc;
                    oacc[qs][ct][2] *= sc; oacc[qs][ct][3] *= sc;
                }
            } else {
                row_l[qs] += ps;
            }
            row_m[qs] = nm;
            f16x4 pk0 = { (f16)p0, (f16)p1, (f16)p2, (f16)p3 };
            f16x4 pk1 = { (f16)p4, (f16)p5, (f16)p6, (f16)p7 };
            *(f16x4*)&Pl[w][qs * 16 + lr][lg * 4]      = pk0;
            *(f16x4*)&Pl[w][qs * 16 + lr][16 + lg * 4] = pk1;
        }

        // ---- PV: O[c][q] += V[c][m] * P[m][q] ----
        f16x8 pf0 = *(const f16x8*)&Pl[w][lr][lg * 8];
        f16x8 pf1 = *(const f16x8*)&Pl[w][16 + lr][lg * 8];
        __builtin_amdgcn_s_setprio(1);
#pragma unroll
        for (int ct = 0; ct < 16; ++ct) {
            f16x8 vf = *(const f16x8*)&Vs[bi][(ct * 16 + lr) * 32 + ((lg ^ ((lr >> 1) & 3))) * 8];
            oacc[0][ct] = __builtin_amdgcn_mfma_f32_16x16x32_f16(vf, pf0, oacc[0][ct], 0, 0, 0);
            oacc[1][ct] = __builtin_amdgcn_mfma_f32_16x16x32_f16(vf, pf1, oacc[1][ct], 0, 0, 0);
        }
        __builtin_amdgcn_s_setprio(0);
        __syncthreads();   // drains stage(it+1); frees buffers for next iter
    }

    // ---- write unnormalized partial + (m,l) ----
#pragma unroll
    for (int qs = 0; qs < 2; ++qs)
#pragma unroll
        for (int ct = 0; ct < 16; ++ct)
#pragma unroll
            for (int r = 0; r < 4; ++r) {
                int cch = ct * 16 + lg * 4 + r;
                Op[(((size_t)ks * 2 + bb) * CD + cch) * ND + q0 + qs * 16 + lr] =
                    (f16)oacc[qs][ct][r];
            }
    if (lg == 0) {
#pragma unroll
        for (int qs = 0; qs < 2; ++qs) {
            int n = q0 + qs * 16 + lr;
            ml[((ks * 2 + bb) * 2 + 0) * ND + n] = row_m[qs];
            ml[((ks * 2 + bb) * 2 + 1) * ND + n] = row_l[qs];
        }
    }
}

// ============================================================================
// Kernel 2b-i: per-n combine weights  wq[ks][b][n] = exp(m-M)/L
// ============================================================================
template<int KSN>
__global__ __launch_bounds__(256)
void k_ml(const float* __restrict__ ml, float* __restrict__ wq)
{
    int i = blockIdx.x * 256 + threadIdx.x;   // i over B*ND
    int b = i / ND, n = i % ND;
    float m[KSN], lv[KSN];
#pragma unroll
    for (int ks = 0; ks < KSN; ++ks) {
        m[ks]  = ml[((ks * 2 + b) * 2 + 0) * ND + n];
        lv[ks] = ml[((ks * 2 + b) * 2 + 1) * ND + n];
    }
    float M = m[0];
#pragma unroll
    for (int ks = 1; ks < KSN; ++ks) M = fmaxf(M, m[ks]);
    float wgt[KSN], L = 0.f;
#pragma unroll
    for (int ks = 0; ks < KSN; ++ks) { wgt[ks] = __expf(m[ks] - M); L += wgt[ks] * lv[ks]; }
    float inv = 1.0f / L;
#pragma unroll
    for (int ks = 0; ks < KSN; ++ks)
        wq[(ks * 2 + b) * ND + n] = wgt[ks] * inv;
}

// ============================================================================
// Kernel 2b-ii: combine split-K partials -> Hb[b][c][n] f16 (vectorized)
// ============================================================================
template<int KSN>
__global__ __launch_bounds__(256)
void k_comb(const f16* __restrict__ Op, const float* __restrict__ wq,
            f16* __restrict__ Hb)
{
    size_t i = (size_t)blockIdx.x * 256 + threadIdx.x;   // one f16x8 each
    int n0 = (int)(i % (ND / 8)) * 8;
    int c  = (int)((i / (ND / 8)) % CD);
    int b  = (int)(i / ((size_t)CD * (ND / 8)));

    float acc[8] = {};
#pragma unroll
    for (int ks = 0; ks < KSN; ++ks) {
        f16x8 o = *(const f16x8*)(Op + (((size_t)ks * 2 + b) * CD + c) * ND + n0);
        const float* wp = wq + (ks * 2 + b) * ND + n0;
        float4 w0 = *(const float4*)wp;
        float4 w1 = *(const float4*)(wp + 4);
        acc[0] += w0.x * (float)o[0]; acc[1] += w0.y * (float)o[1];
        acc[2] += w0.z * (float)o[2]; acc[3] += w0.w * (float)o[3];
        acc[4] += w1.x * (float)o[4]; acc[5] += w1.y * (float)o[5];
        acc[6] += w1.z * (float)o[6]; acc[7] += w1.w * (float)o[7];
    }
    f16x8 h;
#pragma unroll
    for (int u = 0; u < 8; ++u) h[u] = (f16)acc[u];
    *(f16x8*)(Hb + ((size_t)b * CD + c) * ND + n0) = h;
}

// ============================================================================
// Kernel 3: output projection + residual.  Y = Wo@H + bo + x  (f32 out)
// ============================================================================
__global__ __launch_bounds__(256)
void k_proj_o(const f16* __restrict__ Hb, const float* __restrict__ Wo,
              const float* __restrict__ bo, const float* __restrict__ x,
              float* __restrict__ Y)
{
    __shared__ f16 As[64][40];
    __shared__ f16 Bs[64][40];

    const int t  = threadIdx.x;
    const int n0 = blockIdx.x * 64;
    const int o0 = blockIdx.y * 64;
    const int bb = blockIdx.z;

    const int w  = t >> 6;
    const int l  = t & 63;
    const int lr = l & 15;
    const int lg = l >> 4;
    const int wo = (w >> 1) * 32;
    const int wn = (w & 1) * 32;

    const int sl = t & 63;
    const int k8 = (t >> 6) * 8;

    f32x4 acc[2][2] = {};

    for (int ck = 0; ck < CD; ck += 32) {
        __syncthreads();
        {
            const float* s = Wo + (size_t)(o0 + sl) * CD + ck + k8;
            f16x8 v;
#pragma unroll
            for (int u = 0; u < 8; ++u) v[u] = (f16)s[u];
            *(f16x8*)&As[sl][k8] = v;
        }
        {
            const f16* s = Hb + ((size_t)bb * CD + ck + k8) * ND + n0 + sl;
            f16x8 v;
#pragma unroll
            for (int u = 0; u < 8; ++u) v[u] = s[(size_t)u * ND];
            *(f16x8*)&Bs[sl][k8] = v;
        }
        __syncthreads();
        f16x8 a0 = *(const f16x8*)&As[wo + lr][lg * 8];
        f16x8 a1 = *(const f16x8*)&As[wo + 16 + lr][lg * 8];
        f16x8 b0 = *(const f16x8*)&Bs[wn + lr][lg * 8];
        f16x8 b1 = *(const f16x8*)&Bs[wn + 16 + lr][lg * 8];
        acc[0][0] = __builtin_amdgcn_mfma_f32_16x16x32_f16(a0, b0, acc[0][0], 0, 0, 0);
        acc[0][1] = __builtin_amdgcn_mfma_f32_16x16x32_f16(a0, b1, acc[0][1], 0, 0, 0);
        acc[1][0] = __builtin_amdgcn_mfma_f32_16x16x32_f16(a1, b0, acc[1][0], 0, 0, 0);
        acc[1][1] = __builtin_amdgcn_mfma_f32_16x16x32_f16(a1, b1, acc[1][1], 0, 0, 0);
    }

#pragma unroll
    for (int so = 0; so < 2; ++so)
#pragma unroll
        for (int r = 0; r < 4; ++r) {
            int orow  = wo + so * 16 + lg * 4 + r;
            float bv_ = bo[o0 + orow];
#pragma unroll
            for (int sn = 0; sn < 2; ++sn) {
                int ncol   = wn + sn * 16 + lr;
                size_t idx = ((size_t)bb * CD + o0 + orow) * ND + n0 + ncol;
                Y[idx] = acc[so][sn][r] + bv_ + x[idx];
            }
        }
}

// ============================================================================
// Kernel 4: fused GroupNorm + SiLU (stats pass + normalize pass), f32 out
// One block per (group, batch): 8 ch x 4096 = 128 KB, 2nd pass L2-hot.
// ============================================================================
__global__ __launch_bounds__(256)
void k_gn_silu(const float* __restrict__ Y, const float* __restrict__ gamma,
               const float* __restrict__ beta, float* __restrict__ out)
{
    const int g = blockIdx.x, b = blockIdx.y;
    const size_t base = ((size_t)b * CD + g * 8) * ND;
    const float4* src = (const float4*)(Y + base);

    float s = 0.f, s2 = 0.f;
    for (int i = threadIdx.x; i < (8 * ND) / 4; i += 256) {
        float4 v = src[i];
        s  += v.x + v.y + v.z + v.w;
        s2 += v.x * v.x + v.y * v.y + v.z * v.z + v.w * v.w;
    }
#pragma unroll
    for (int m = 1; m < 64; m <<= 1) {
        s  += __shfl_xor(s, m);
        s2 += __shfl_xor(s2, m);
    }
    __shared__ float red[8];
    __shared__ float mr[2];
    if ((threadIdx.x & 63) == 0) {
        red[(threadIdx.x >> 6) * 2]     = s;
        red[(threadIdx.x >> 6) * 2 + 1] = s2;
    }
    __syncthreads();
    if (threadIdx.x == 0) {
        float S  = red[0] + red[2] + red[4] + red[6];
        float S2 = red[1] + red[3] + red[5] + red[7];
        float mean = S / 32768.f;
        float var  = S2 / 32768.f - mean * mean;
        mr[0] = mean;
        mr[1] = rsqrtf(var + 1e-5f);
    }
    __syncthreads();
    const float mean = mr[0], rstd = mr[1];

    float4* dst = (float4*)(out + base);
    for (int i = threadIdx.x; i < (8 * ND) / 4; i += 256) {
        int c = g * 8 + (i >> 10);            // ND/4 = 1024 float4 per channel
        float ga = gamma[c], be = beta[c];
        float4 v = src[i];
        float in[4] = { v.x, v.y, v.z, v.w };
        float ob[4];
#pragma unroll
        for (int u = 0; u < 4; ++u) {
            float yn = (in[u] - mean) * rstd * ga + be;
            float sg = 1.0f / (1.0f + __expf(-yn));
            ob[u] = yn * sg;
        }
        dst[i] = *(float4*)ob;
    }
}

// ============================================================================
extern "C" void kernel_launch(void* const* d_in, const int* in_sizes, int n_in,
                              void* d_out, int out_size, void* d_ws, size_t ws_size,
                              hipStream_t stream)
{
    const float* x     = (const float*)d_in[0];
    const float* Wq    = (const float*)d_in[1];
    const float* bq    = (const float*)d_in[2];
    const float* Wk    = (const float*)d_in[3];
    const float* bk    = (const float*)d_in[4];
    const float* Wv    = (const float*)d_in[5];
    const float* bv    = (const float*)d_in[6];
    const float* Wo    = (const float*)d_in[7];
    const float* bo    = (const float*)d_in[8];
    const float* gamma = (const float*)d_in[9];
    const float* beta  = (const float*)d_in[10];

    char* ws = (char*)d_ws;
    f16* Qt = (f16*)(ws);                    //  0..4 MiB   [B][N][C]
    f16* Kt = (f16*)(ws + (4u << 20));       //  4..8 MiB   [B][N][C]
    f16* Vb = (f16*)(ws + (8u << 20));       //  8..12 MiB  [B][C][N]
    f16* Hb = (f16*)(ws + (12u << 20));      // 12..16 MiB  [B][C][N]
    f16* Op = (f16*)(ws + (16u << 20));      // 16.. MiB    [KSN][B][C][N]
    float* Y = (float*)(ws + (16u << 20));   // reuses Op region after combine

    const bool big = ws_size >= (50ull << 20);

    k_proj_qkv<<<dim3(64, 4, 2), 256, 0, stream>>>(x, Wq, bq, Wk, bk, Wv, bv, Qt, Kt, Vb);

    if (big) {
        constexpr int KSN = 8;
        float* ml    = (float*)(ws + (48u << 20));                // 512 KB
        float* wq    = (float*)(ws + (48u << 20) + (768u << 10)); // 256 KB
        k_attn<KSN><<<dim3(32 * KSN * 2), 256, 0, stream>>>(Qt, Kt, Vb, Op, ml);
        k_ml<KSN><<<dim3((2 * ND) / 256), 256, 0, stream>>>(ml, wq);
        k_comb<KSN><<<dim3((2 * CD * ND / 8) / 256), 256, 0, stream>>>(Op, wq, Hb);
        k_proj_o<<<dim3(64, 4, 2), 256, 0, stream>>>(Hb, Wo, bo, x, Y);
        k_gn_silu<<<dim3(GD, 2), 256, 0, stream>>>(Y, gamma, beta, (float*)d_out);
    } else {
        constexpr int KSN = 4;
        float* ml    = (float*)(ws + (32u << 20));                // 256 KB
        float* wq    = (float*)(ws + (32u << 20) + (512u << 10)); // 128 KB
        k_attn<KSN><<<dim3(32 * KSN * 2), 256, 0, stream>>>(Qt, Kt, Vb, Op, ml);
        k_ml<KSN><<<dim3((2 * ND) / 256), 256, 0, stream>>>(ml, wq);
        k_comb<KSN><<<dim3((2 * CD * ND / 8) / 256), 256, 0, stream>>>(Op, wq, Hb);
        k_proj_o<<<dim3(64, 4, 2), 256, 0, stream>>>(Hb, Wo, bo, x, Y);
        k_gn_silu<<<dim3(GD, 2), 256, 0, stream>>>(Y, gamma, beta, (float*)d_out);
    }
}

// Round 8
// 117.688 us; speedup vs baseline: 1.0562x; 1.0295x over previous
//
#include <hip/hip_runtime.h>
#include <hip/hip_bf16.h>

typedef _Float16 f16;
typedef __attribute__((ext_vector_type(4))) _Float16 f16x4;
typedef __attribute__((ext_vector_type(8))) _Float16 f16x8;
typedef __attribute__((ext_vector_type(4))) float f32x4;

#define CD 256
#define ND 4096
#define GD 32
#define KVB 32          // keys per iteration

// async global->LDS, 16B per lane, lds dest must be wave-uniform base
__device__ __forceinline__ void gl_lds16(const f16* g, f16* l) {
    __builtin_amdgcn_global_load_lds(
        (const __attribute__((address_space(1))) unsigned int*)g,
        (__attribute__((address_space(3))) unsigned int*)l,
        16, 0, 0);
}

// ============================================================================
// Kernel 1: fused QKV projection.  p[b,o,n] = sum_c W[o,c] x[b,c,n] + bias[o]
// Q,K written TRANSPOSED [b][n][c] f16; V natural [b][c][n] f16.
// ============================================================================
__global__ __launch_bounds__(256)
void k_proj_qkv(const float* __restrict__ x,
                const float* __restrict__ Wq, const float* __restrict__ bq,
                const float* __restrict__ Wk, const float* __restrict__ bk,
                const float* __restrict__ Wv, const float* __restrict__ bv,
                f16* __restrict__ Qt, f16* __restrict__ Kt, f16* __restrict__ Vb)
{
    __shared__ f16 As[3][64][40];
    __shared__ f16 Bs[64][40];
    __shared__ f16 Ts[64][72];

    const int t  = threadIdx.x;
    const int n0 = blockIdx.x * 64;
    const int o0 = blockIdx.y * 64;
    const int bb = blockIdx.z;

    const float* Ws[3] = { Wq, Wk, Wv };
    const float* bs[3] = { bq, bk, bv };

    const int w  = t >> 6;
    const int l  = t & 63;
    const int lr = l & 15;
    const int lg = l >> 4;
    const int wo = (w >> 1) * 32;
    const int wn = (w & 1) * 32;

    const int sl = t & 63;
    const int k8 = (t >> 6) * 8;

    f32x4 acc[3][2][2] = {};

    for (int ck = 0; ck < CD; ck += 32) {
        __syncthreads();
#pragma unroll
        for (int p = 0; p < 3; ++p) {
            const float* s = Ws[p] + (size_t)(o0 + sl) * CD + ck + k8;
            f16x8 v;
#pragma unroll
            for (int u = 0; u < 8; ++u) v[u] = (f16)s[u];
            *(f16x8*)&As[p][sl][k8] = v;
        }
        {
            const float* s = x + ((size_t)bb * CD + ck + k8) * ND + n0 + sl;
            f16x8 v;
#pragma unroll
            for (int u = 0; u < 8; ++u) v[u] = (f16)s[(size_t)u * ND];
            *(f16x8*)&Bs[sl][k8] = v;
        }
        __syncthreads();
        f16x8 b0 = *(const f16x8*)&Bs[wn + lr][lg * 8];
        f16x8 b1 = *(const f16x8*)&Bs[wn + 16 + lr][lg * 8];
#pragma unroll
        for (int p = 0; p < 3; ++p) {
            f16x8 a0 = *(const f16x8*)&As[p][wo + lr][lg * 8];
            f16x8 a1 = *(const f16x8*)&As[p][wo + 16 + lr][lg * 8];
            acc[p][0][0] = __builtin_amdgcn_mfma_f32_16x16x32_f16(a0, b0, acc[p][0][0], 0, 0, 0);
            acc[p][0][1] = __builtin_amdgcn_mfma_f32_16x16x32_f16(a0, b1, acc[p][0][1], 0, 0, 0);
            acc[p][1][0] = __builtin_amdgcn_mfma_f32_16x16x32_f16(a1, b0, acc[p][1][0], 0, 0, 0);
            acc[p][1][1] = __builtin_amdgcn_mfma_f32_16x16x32_f16(a1, b1, acc[p][1][1], 0, 0, 0);
        }
    }

    // Q, K: transpose via Ts then coalesced [n][c] writes
#pragma unroll
    for (int p = 0; p < 2; ++p) {
        __syncthreads();
#pragma unroll
        for (int so = 0; so < 2; ++so)
#pragma unroll
            for (int r = 0; r < 4; ++r) {
                int orow  = wo + so * 16 + lg * 4 + r;
                float bv_ = bs[p][o0 + orow];
#pragma unroll
                for (int sn = 0; sn < 2; ++sn)
                    Ts[orow][wn + sn * 16 + lr] = (f16)(acc[p][so][sn][r] + bv_);
            }
        __syncthreads();
        f16* dst = (p == 0) ? Qt : Kt;
        int n  = t >> 2;
        int o8 = (t & 3) * 16;
        f16 tmp[16];
#pragma unroll
        for (int u = 0; u < 16; ++u) tmp[u] = Ts[o8 + u][n];
        f16* g = dst + ((size_t)bb * ND + n0 + n) * CD + o0 + o8;
        *(f16x8*)g       = *(f16x8*)&tmp[0];
        *(f16x8*)(g + 8) = *(f16x8*)&tmp[8];
    }
    // V: direct [c][n] writes
#pragma unroll
    for (int so = 0; so < 2; ++so)
#pragma unroll
        for (int r = 0; r < 4; ++r) {
            int orow  = wo + so * 16 + lg * 4 + r;
            float bv_ = bv[o0 + orow];
#pragma unroll
            for (int sn = 0; sn < 2; ++sn) {
                int ncol = wn + sn * 16 + lr;
                Vb[((size_t)bb * CD + o0 + orow) * ND + n0 + ncol] =
                    (f16)(acc[2][so][sn][r] + bv_);
            }
        }
}

// ============================================================================
// Kernel 2: flash attention, split-K (template KSN).
// 4 waves x 32 queries (QBLK=128).  KVB=32 keys/iter, double-buffered LDS,
// 2 blocks/CU.  SWAPPED QK^T: lane-local softmax.  Defer-max THR=5.
// XCD-pinned flat grid.  Main loop unrolled x2 so the dbuf index is a
// compile-time constant (LDS address = base + immediate).
// ============================================================================
template<int KSN>
__global__ __launch_bounds__(256, 2)
void k_attn(const f16* __restrict__ Qt, const f16* __restrict__ Kt,
            const f16* __restrict__ Vb, f16* __restrict__ Op,
            float* __restrict__ ml)
{
    __shared__ f16 Ks[2][32 * 256];   // [buf][row][chunk16B ^ (row&7)]  2x16 KB
    __shared__ f16 Vs[2][256 * 32];   // [buf][c][chunk16B ^ ((c>>1)&3)] 2x16 KB
    __shared__ f16 Pl[4][32][40];     // per-wave P [q_local][m]

    const int t  = threadIdx.x;
    const int w  = t >> 6;           // 0..3
    const int l  = t & 63;
    const int lr = l & 15;
    const int lg = l >> 4;

    // ---- XCD-pinned decode ----
    const int bid = blockIdx.x;
    int bb, ks, qi;
    if constexpr (KSN == 8) {
        int xcd = bid & 7;
        bb = xcd & 1;
        ks = (xcd >> 1) | ((bid >> 8) << 2);
        qi = (bid >> 3) & 31;
    } else {   // KSN == 4
        bb = bid & 1;
        ks = (bid >> 1) & 3;
        qi = bid >> 3;
    }
    const int q0 = qi * 128 + w * 32;

    // Q fragments in registers: 2 q-subgroups x 8 k-chunks
    f16x8 qf[2][8];
#pragma unroll
    for (int qs = 0; qs < 2; ++qs)
#pragma unroll
        for (int kc = 0; kc < 8; ++kc)
            qf[qs][kc] = *(const f16x8*)(Qt + ((size_t)bb * ND + q0 + qs * 16 + lr) * CD + kc * 32 + lg * 8);

    f32x4 oacc[2][16] = {};
    float row_m[2] = { -3.0e38f, -3.0e38f };
    float row_l[2] = { 0.f, 0.f };

    const int kv0 = ks * (ND / KSN);
    const f16* ktb = Kt + (size_t)bb * ND * CD;
    const f16* vbb = Vb + (size_t)bb * CD * ND;

    // per-lane loop-invariant staging offsets (elements)
    int koff[4], voff[4];
#pragma unroll
    for (int j = 0; j < 4; ++j) {
        int v   = (w * 4 + j) * 64 + l;
        int row = v >> 5;
        int ch  = (v & 31) ^ (row & 7);
        koff[j] = row * CD + ch * 8;
        int c   = v >> 2;
        int u   = (v & 3) ^ ((c >> 1) & 3);
        voff[j] = c * ND + u * 8;
    }

    auto stage = [&](int m0, int bi) {
#pragma unroll
        for (int j = 0; j < 4; ++j)
            gl_lds16(ktb + (size_t)m0 * CD + koff[j], &Ks[bi][(w * 4 + j) * 512]);
#pragma unroll
        for (int j = 0; j < 4; ++j)
            gl_lds16(vbb + m0 + voff[j], &Vs[bi][(w * 4 + j) * 512]);
    };

    stage(kv0, 0);
    __syncthreads();    // drains vmcnt; tile 0 resident

    const int NIT = (ND / KSN) / KVB;
#pragma unroll 2
    for (int it = 0; it < NIT; ++it) {
        const int bi = it & 1;     // compile-time after unroll-2
        if (it + 1 < NIT) stage(kv0 + (it + 1) * KVB, bi ^ 1);

        // ---- scores S[m][q]: 2 m-subtiles x 2 q-subgroups ----
        f32x4 s[2][2] = {};
        __builtin_amdgcn_s_setprio(1);
#pragma unroll
        for (int kc = 0; kc < 8; ++kc) {
            int chs = ((kc * 4 + lg) ^ (lr & 7)) * 8;
            f16x8 k0 = *(const f16x8*)&Ks[bi][(lr) * 256 + chs];
            f16x8 k1 = *(const f16x8*)&Ks[bi][(16 + lr) * 256 + chs];
            s[0][0] = __builtin_amdgcn_mfma_f32_16x16x32_f16(k0, qf[0][kc], s[0][0], 0, 0, 0);
            s[1][0] = __builtin_amdgcn_mfma_f32_16x16x32_f16(k1, qf[0][kc], s[1][0], 0, 0, 0);
            s[0][1] = __builtin_amdgcn_mfma_f32_16x16x32_f16(k0, qf[1][kc], s[0][1], 0, 0, 0);
            s[1][1] = __builtin_amdgcn_mfma_f32_16x16x32_f16(k1, qf[1][kc], s[1][1], 0, 0, 0);
        }
        __builtin_amdgcn_s_setprio(0);

        // ---- lane-local online softmax per q-subgroup (defer-max THR=5) ----
#pragma unroll
        for (int qs = 0; qs < 2; ++qs) {
            float pm = fmaxf(
                fmaxf(fmaxf(s[0][qs][0], s[0][qs][1]), fmaxf(s[0][qs][2], s[0][qs][3])),
                fmaxf(fmaxf(s[1][qs][0], s[1][qs][1]), fmaxf(s[1][qs][2], s[1][qs][3])));
            pm = fmaxf(pm, __shfl_xor(pm, 16));
            pm = fmaxf(pm, __shfl_xor(pm, 32));
            bool need = (pm > row_m[qs] + 5.0f);   // defer small max growth
            float nm  = need ? pm : row_m[qs];
            float p0 = __expf(s[0][qs][0] - nm);
            float p1 = __expf(s[0][qs][1] - nm);
            float p2 = __expf(s[0][qs][2] - nm);
            float p3 = __expf(s[0][qs][3] - nm);
            float p4 = __expf(s[1][qs][0] - nm);
            float p5 = __expf(s[1][qs][1] - nm);
            float p6 = __expf(s[1][qs][2] - nm);
            float p7 = __expf(s[1][qs][3] - nm);
            float ps = ((p0 + p1) + (p2 + p3)) + ((p4 + p5) + (p6 + p7));
            ps += __shfl_xor(ps, 16);
            ps += __shfl_xor(ps, 32);
            if (__any(need)) {
                float sc = __expf(row_m[qs] - nm);   // == 1 for lanes w/o change
                row_l[qs] = row_l[qs] * sc + ps;
#pragma unroll
                for (int ct = 0; ct < 16; ++ct) {
                    oacc[qs][ct][0] *= sc; oacc[qs][ct][1] *= sc;
                    oacc[qs][ct][2] *= sc; oacc[qs][ct][3] *= sc;
                }
            } else {
                row_l[qs] += ps;
            }
            row_m[qs] = nm;
            f16x4 pk0 = { (f16)p0, (f16)p1, (f16)p2, (f16)p3 };
            f16x4 pk1 = { (f16)p4, (f16)p5, (f16)p6, (f16)p7 };
            *(f16x4*)&Pl[w][qs * 16 + lr][lg * 4]      = pk0;
            *(f16x4*)&Pl[w][qs * 16 + lr][16 + lg * 4] = pk1;
        }

        // ---- PV: O[c][q] += V[c][m] * P[m][q] ----
        f16x8 pf0 = *(const f16x8*)&Pl[w][lr][lg * 8];
        f16x8 pf1 = *(const f16x8*)&Pl[w][16 + lr][lg * 8];
        __builtin_amdgcn_s_setprio(1);
#pragma unroll
        for (int ct = 0; ct < 16; ++ct) {
            f16x8 vf = *(const f16x8*)&Vs[bi][(ct * 16 + lr) * 32 + ((lg ^ ((lr >> 1) & 3))) * 8];
            oacc[0][ct] = __builtin_amdgcn_mfma_f32_16x16x32_f16(vf, pf0, oacc[0][ct], 0, 0, 0);
            oacc[1][ct] = __builtin_amdgcn_mfma_f32_16x16x32_f16(vf, pf1, oacc[1][ct], 0, 0, 0);
        }
        __builtin_amdgcn_s_setprio(0);
        __syncthreads();   // drains stage(it+1); frees buffers for next iter
    }

    // ---- write unnormalized partial + (m,l) ----
#pragma unroll
    for (int qs = 0; qs < 2; ++qs)
#pragma unroll
        for (int ct = 0; ct < 16; ++ct)
#pragma unroll
            for (int r = 0; r < 4; ++r) {
                int cch = ct * 16 + lg * 4 + r;
                Op[(((size_t)ks * 2 + bb) * CD + cch) * ND + q0 + qs * 16 + lr] =
                    (f16)oacc[qs][ct][r];
            }
    if (lg == 0) {
#pragma unroll
        for (int qs = 0; qs < 2; ++qs) {
            int n = q0 + qs * 16 + lr;
            ml[((ks * 2 + bb) * 2 + 0) * ND + n] = row_m[qs];
            ml[((ks * 2 + bb) * 2 + 1) * ND + n] = row_l[qs];
        }
    }
}

// ============================================================================
// Kernel 2b-i: per-n combine weights  wq[ks][b][n] = exp(m-M)/L
// ============================================================================
template<int KSN>
__global__ __launch_bounds__(256)
void k_ml(const float* __restrict__ ml, float* __restrict__ wq)
{
    int i = blockIdx.x * 256 + threadIdx.x;   // i over B*ND
    int b = i / ND, n = i % ND;
    float m[KSN], lv[KSN];
#pragma unroll
    for (int ks = 0; ks < KSN; ++ks) {
        m[ks]  = ml[((ks * 2 + b) * 2 + 0) * ND + n];
        lv[ks] = ml[((ks * 2 + b) * 2 + 1) * ND + n];
    }
    float M = m[0];
#pragma unroll
    for (int ks = 1; ks < KSN; ++ks) M = fmaxf(M, m[ks]);
    float wgt[KSN], L = 0.f;
#pragma unroll
    for (int ks = 0; ks < KSN; ++ks) { wgt[ks] = __expf(m[ks] - M); L += wgt[ks] * lv[ks]; }
    float inv = 1.0f / L;
#pragma unroll
    for (int ks = 0; ks < KSN; ++ks)
        wq[(ks * 2 + b) * ND + n] = wgt[ks] * inv;
}

// ============================================================================
// Kernel 2b-ii: combine split-K partials -> Hb[b][c][n] f16 (vectorized)
// ============================================================================
template<int KSN>
__global__ __launch_bounds__(256)
void k_comb(const f16* __restrict__ Op, const float* __restrict__ wq,
            f16* __restrict__ Hb)
{
    size_t i = (size_t)blockIdx.x * 256 + threadIdx.x;   // one f16x8 each
    int n0 = (int)(i % (ND / 8)) * 8;
    int c  = (int)((i / (ND / 8)) % CD);
    int b  = (int)(i / ((size_t)CD * (ND / 8)));

    float acc[8] = {};
#pragma unroll
    for (int ks = 0; ks < KSN; ++ks) {
        f16x8 o = *(const f16x8*)(Op + (((size_t)ks * 2 + b) * CD + c) * ND + n0);
        const float* wp = wq + (ks * 2 + b) * ND + n0;
        float4 w0 = *(const float4*)wp;
        float4 w1 = *(const float4*)(wp + 4);
        acc[0] += w0.x * (float)o[0]; acc[1] += w0.y * (float)o[1];
        acc[2] += w0.z * (float)o[2]; acc[3] += w0.w * (float)o[3];
        acc[4] += w1.x * (float)o[4]; acc[5] += w1.y * (float)o[5];
        acc[6] += w1.z * (float)o[6]; acc[7] += w1.w * (float)o[7];
    }
    f16x8 h;
#pragma unroll
    for (int u = 0; u < 8; ++u) h[u] = (f16)acc[u];
    *(f16x8*)(Hb + ((size_t)b * CD + c) * ND + n0) = h;
}

// ============================================================================
// Kernel 3: output projection + residual.  Y = Wo@H + bo + x  (f32 out)
// Also emits deterministic per-block GroupNorm partial sums:
//   part[b][group][bx][{s,s2}]  (each written by exactly one block)
// ============================================================================
__global__ __launch_bounds__(256)
void k_proj_o(const f16* __restrict__ Hb, const float* __restrict__ Wo,
              const float* __restrict__ bo, const float* __restrict__ x,
              float* __restrict__ Y, float* __restrict__ part)
{
    __shared__ f16 As[64][40];
    __shared__ f16 Bs[64][40];
    __shared__ float rs[4][2][2][2];   // [wave][so][lg>>1][{s,s2}]

    const int t  = threadIdx.x;
    const int n0 = blockIdx.x * 64;
    const int o0 = blockIdx.y * 64;
    const int bb = blockIdx.z;

    const int w  = t >> 6;
    const int l  = t & 63;
    const int lr = l & 15;
    const int lg = l >> 4;
    const int wo = (w >> 1) * 32;
    const int wn = (w & 1) * 32;

    const int sl = t & 63;
    const int k8 = (t >> 6) * 8;

    f32x4 acc[2][2] = {};

    for (int ck = 0; ck < CD; ck += 32) {
        __syncthreads();
        {
            const float* s = Wo + (size_t)(o0 + sl) * CD + ck + k8;
            f16x8 v;
#pragma unroll
            for (int u = 0; u < 8; ++u) v[u] = (f16)s[u];
            *(f16x8*)&As[sl][k8] = v;
        }
        {
            const f16* s = Hb + ((size_t)bb * CD + ck + k8) * ND + n0 + sl;
            f16x8 v;
#pragma unroll
            for (int u = 0; u < 8; ++u) v[u] = s[(size_t)u * ND];
            *(f16x8*)&Bs[sl][k8] = v;
        }
        __syncthreads();
        f16x8 a0 = *(const f16x8*)&As[wo + lr][lg * 8];
        f16x8 a1 = *(const f16x8*)&As[wo + 16 + lr][lg * 8];
        f16x8 b0 = *(const f16x8*)&Bs[wn + lr][lg * 8];
        f16x8 b1 = *(const f16x8*)&Bs[wn + 16 + lr][lg * 8];
        acc[0][0] = __builtin_amdgcn_mfma_f32_16x16x32_f16(a0, b0, acc[0][0], 0, 0, 0);
        acc[0][1] = __builtin_amdgcn_mfma_f32_16x16x32_f16(a0, b1, acc[0][1], 0, 0, 0);
        acc[1][0] = __builtin_amdgcn_mfma_f32_16x16x32_f16(a1, b0, acc[1][0], 0, 0, 0);
        acc[1][1] = __builtin_amdgcn_mfma_f32_16x16x32_f16(a1, b1, acc[1][1], 0, 0, 0);
    }

#pragma unroll
    for (int so = 0; so < 2; ++so) {
        float ls = 0.f, ls2 = 0.f;
#pragma unroll
        for (int r = 0; r < 4; ++r) {
            int orow  = wo + so * 16 + lg * 4 + r;
            float bv_ = bo[o0 + orow];
#pragma unroll
            for (int sn = 0; sn < 2; ++sn) {
                int ncol   = wn + sn * 16 + lr;
                size_t idx = ((size_t)bb * CD + o0 + orow) * ND + n0 + ncol;
                float v = acc[so][sn][r] + bv_ + x[idx];
                Y[idx] = v;
                ls  += v;
                ls2 += v * v;
            }
        }
        // deterministic reduce over lanes sharing the same group:
        // lr (xor 1,2,4,8) and lg&1 (xor 16)
#pragma unroll
        for (int m = 1; m <= 16; m <<= 1) {
            ls  += __shfl_xor(ls, m);
            ls2 += __shfl_xor(ls2, m);
        }
        if ((l & 31) == 0) {
            rs[w][so][l >> 5][0] = ls;
            rs[w][so][l >> 5][1] = ls2;
        }
    }
    __syncthreads();
    if (t < 16) {
        int gl = t >> 1, st = t & 1;
        int a = gl >> 2, so = (gl >> 1) & 1, lh = gl & 1;
        float v = rs[2 * a][so][lh][st] + rs[2 * a + 1][so][lh][st];
        part[(((size_t)bb * GD + (o0 >> 3) + gl) * 64 + blockIdx.x) * 2 + st] = v;
    }
}

// ============================================================================
// Kernel 4: GroupNorm (from partials) + SiLU, single pass, f32 out
// grid (32 groups, 2 batch, 4 n-quarters) = 256 blocks
// ============================================================================
__global__ __launch_bounds__(256)
void k_gn_silu(const float* __restrict__ Y, const float* __restrict__ part,
               const float* __restrict__ gamma, const float* __restrict__ beta,
               float* __restrict__ out)
{
    const int g  = blockIdx.x, b = blockIdx.y, nq = blockIdx.z;
    const int t  = threadIdx.x;

    __shared__ float mr[2];
    if (t < 64) {
        float s  = part[(((size_t)b * GD + g) * 64 + t) * 2 + 0];
        float s2 = part[(((size_t)b * GD + g) * 64 + t) * 2 + 1];
#pragma unroll
        for (int m = 1; m < 64; m <<= 1) {
            s  += __shfl_xor(s, m);
            s2 += __shfl_xor(s2, m);
        }
        if (t == 0) {
            float mean = s / 32768.f;
            float var  = s2 / 32768.f - mean * mean;
            mr[0] = mean;
            mr[1] = rsqrtf(var + 1e-5f);
        }
    }
    __syncthreads();
    const float mean = mr[0], rstd = mr[1];

    const size_t base = ((size_t)b * CD + g * 8) * ND;
    const float4* src = (const float4*)(Y + base);
    float4* dst = (float4*)(out + base);

    // 8 channels x 1024 n = 2048 float4 per block
    for (int i = t; i < 2048; i += 256) {
        int ch = i >> 8;                       // 256 float4 per channel-quarter
        int nn = i & 255;
        int f4 = ch * (ND / 4) + nq * 256 + nn;
        int c  = g * 8 + ch;
        float ga = gamma[c], be = beta[c];
        float4 v = src[f4];
        float in[4] = { v.x, v.y, v.z, v.w };
        float ob[4];
#pragma unroll
        for (int u = 0; u < 4; ++u) {
            float yn = (in[u] - mean) * rstd * ga + be;
            float sg = 1.0f / (1.0f + __expf(-yn));
            ob[u] = yn * sg;
        }
        dst[f4] = *(float4*)ob;
    }
}

// ============================================================================
extern "C" void kernel_launch(void* const* d_in, const int* in_sizes, int n_in,
                              void* d_out, int out_size, void* d_ws, size_t ws_size,
                              hipStream_t stream)
{
    const float* x     = (const float*)d_in[0];
    const float* Wq    = (const float*)d_in[1];
    const float* bq    = (const float*)d_in[2];
    const float* Wk    = (const float*)d_in[3];
    const float* bk    = (const float*)d_in[4];
    const float* Wv    = (const float*)d_in[5];
    const float* bv    = (const float*)d_in[6];
    const float* Wo    = (const float*)d_in[7];
    const float* bo    = (const float*)d_in[8];
    const float* gamma = (const float*)d_in[9];
    const float* beta  = (const float*)d_in[10];

    char* ws = (char*)d_ws;
    f16* Qt = (f16*)(ws);                    //  0..4 MiB   [B][N][C]
    f16* Kt = (f16*)(ws + (4u << 20));       //  4..8 MiB   [B][N][C]
    f16* Vb = (f16*)(ws + (8u << 20));       //  8..12 MiB  [B][C][N]
    f16* Hb = (f16*)(ws + (12u << 20));      // 12..16 MiB  [B][C][N]
    f16* Op = (f16*)(ws + (16u << 20));      // 16.. MiB    [KSN][B][C][N]
    float* Y = (float*)(ws + (16u << 20));   // reuses Op region after combine

    const bool big = ws_size >= (50ull << 20);

    k_proj_qkv<<<dim3(64, 4, 2), 256, 0, stream>>>(x, Wq, bq, Wk, bk, Wv, bv, Qt, Kt, Vb);

    if (big) {
        constexpr int KSN = 8;
        float* ml   = (float*)(ws + (48u << 20));                 // 512 KB
        float* wq   = (float*)(ws + (48u << 20) + (768u << 10));  // 256 KB
        float* part = (float*)(ws + (49u << 20) + (512u << 10));  // 32 KB
        k_attn<KSN><<<dim3(32 * KSN * 2), 256, 0, stream>>>(Qt, Kt, Vb, Op, ml);
        k_ml<KSN><<<dim3((2 * ND) / 256), 256, 0, stream>>>(ml, wq);
        k_comb<KSN><<<dim3((2 * CD * ND / 8) / 256), 256, 0, stream>>>(Op, wq, Hb);
        k_proj_o<<<dim3(64, 4, 2), 256, 0, stream>>>(Hb, Wo, bo, x, Y, part);
        k_gn_silu<<<dim3(GD, 2, 4), 256, 0, stream>>>(Y, part, gamma, beta, (float*)d_out);
    } else {
        constexpr int KSN = 4;
        float* ml   = (float*)(ws + (32u << 20));                 // 256 KB
        float* wq   = (float*)(ws + (32u << 20) + (512u << 10));  // 128 KB
        float* part = (float*)(ws + (33u << 20));                 // 32 KB
        k_attn<KSN><<<dim3(32 * KSN * 2), 256, 0, stream>>>(Qt, Kt, Vb, Op, ml);
        k_ml<KSN><<<dim3((2 * ND) / 256), 256, 0, stream>>>(ml, wq);
        k_comb<KSN><<<dim3((2 * CD * ND / 8) / 256), 256, 0, stream>>>(Op, wq, Hb);
        k_proj_o<<<dim3(64, 4, 2), 256, 0, stream>>>(Hb, Wo, bo, x, Y, part);
        k_gn_silu<<<dim3(GD, 2, 4), 256, 0, stream>>>(Y, part, gamma, beta, (float*)d_out);
    }
}

// Round 9
// 104.868 us; speedup vs baseline: 1.1853x; 1.1222x over previous
//
#include <hip/hip_runtime.h>
#include <hip/hip_bf16.h>

typedef _Float16 f16;
typedef __attribute__((ext_vector_type(4))) _Float16 f16x4;
typedef __attribute__((ext_vector_type(8))) _Float16 f16x8;
typedef __attribute__((ext_vector_type(4))) float f32x4;

#define CD 256
#define ND 4096
#define GD 32
#define KVB 32          // keys per iteration

// async global->LDS, 16B per lane, lds dest must be wave-uniform base
__device__ __forceinline__ void gl_lds16(const f16* g, f16* l) {
    __builtin_amdgcn_global_load_lds(
        (const __attribute__((address_space(1))) unsigned int*)g,
        (__attribute__((address_space(3))) unsigned int*)l,
        16, 0, 0);
}

// ============================================================================
// Kernel 1: fused QKV projection.  p[b,o,n] = sum_c W[o,c] x[b,c,n] + bias[o]
// Q,K written TRANSPOSED [b][n][c] f16; V natural [b][c][n] f16.
// ============================================================================
__global__ __launch_bounds__(256)
void k_proj_qkv(const float* __restrict__ x,
                const float* __restrict__ Wq, const float* __restrict__ bq,
                const float* __restrict__ Wk, const float* __restrict__ bk,
                const float* __restrict__ Wv, const float* __restrict__ bv,
                f16* __restrict__ Qt, f16* __restrict__ Kt, f16* __restrict__ Vb)
{
    __shared__ f16 As[3][64][40];
    __shared__ f16 Bs[64][40];
    __shared__ f16 Ts[64][72];

    const int t  = threadIdx.x;
    const int n0 = blockIdx.x * 64;
    const int o0 = blockIdx.y * 64;
    const int bb = blockIdx.z;

    const float* Ws[3] = { Wq, Wk, Wv };
    const float* bs[3] = { bq, bk, bv };

    const int w  = t >> 6;
    const int l  = t & 63;
    const int lr = l & 15;
    const int lg = l >> 4;
    const int wo = (w >> 1) * 32;
    const int wn = (w & 1) * 32;

    const int sl = t & 63;
    const int k8 = (t >> 6) * 8;

    f32x4 acc[3][2][2] = {};

    for (int ck = 0; ck < CD; ck += 32) {
        __syncthreads();
#pragma unroll
        for (int p = 0; p < 3; ++p) {
            const float* s = Ws[p] + (size_t)(o0 + sl) * CD + ck + k8;
            f16x8 v;
#pragma unroll
            for (int u = 0; u < 8; ++u) v[u] = (f16)s[u];
            *(f16x8*)&As[p][sl][k8] = v;
        }
        {
            const float* s = x + ((size_t)bb * CD + ck + k8) * ND + n0 + sl;
            f16x8 v;
#pragma unroll
            for (int u = 0; u < 8; ++u) v[u] = (f16)s[(size_t)u * ND];
            *(f16x8*)&Bs[sl][k8] = v;
        }
        __syncthreads();
        f16x8 b0 = *(const f16x8*)&Bs[wn + lr][lg * 8];
        f16x8 b1 = *(const f16x8*)&Bs[wn + 16 + lr][lg * 8];
#pragma unroll
        for (int p = 0; p < 3; ++p) {
            f16x8 a0 = *(const f16x8*)&As[p][wo + lr][lg * 8];
            f16x8 a1 = *(const f16x8*)&As[p][wo + 16 + lr][lg * 8];
            acc[p][0][0] = __builtin_amdgcn_mfma_f32_16x16x32_f16(a0, b0, acc[p][0][0], 0, 0, 0);
            acc[p][0][1] = __builtin_amdgcn_mfma_f32_16x16x32_f16(a0, b1, acc[p][0][1], 0, 0, 0);
            acc[p][1][0] = __builtin_amdgcn_mfma_f32_16x16x32_f16(a1, b0, acc[p][1][0], 0, 0, 0);
            acc[p][1][1] = __builtin_amdgcn_mfma_f32_16x16x32_f16(a1, b1, acc[p][1][1], 0, 0, 0);
        }
    }

    // Q, K: transpose via Ts then coalesced [n][c] writes
#pragma unroll
    for (int p = 0; p < 2; ++p) {
        __syncthreads();
#pragma unroll
        for (int so = 0; so < 2; ++so)
#pragma unroll
            for (int r = 0; r < 4; ++r) {
                int orow  = wo + so * 16 + lg * 4 + r;
                float bv_ = bs[p][o0 + orow];
#pragma unroll
                for (int sn = 0; sn < 2; ++sn)
                    Ts[orow][wn + sn * 16 + lr] = (f16)(acc[p][so][sn][r] + bv_);
            }
        __syncthreads();
        f16* dst = (p == 0) ? Qt : Kt;
        int n  = t >> 2;
        int o8 = (t & 3) * 16;
        f16 tmp[16];
#pragma unroll
        for (int u = 0; u < 16; ++u) tmp[u] = Ts[o8 + u][n];
        f16* g = dst + ((size_t)bb * ND + n0 + n) * CD + o0 + o8;
        *(f16x8*)g       = *(f16x8*)&tmp[0];
        *(f16x8*)(g + 8) = *(f16x8*)&tmp[8];
    }
    // V: direct [c][n] writes
#pragma unroll
    for (int so = 0; so < 2; ++so)
#pragma unroll
        for (int r = 0; r < 4; ++r) {
            int orow  = wo + so * 16 + lg * 4 + r;
            float bv_ = bv[o0 + orow];
#pragma unroll
            for (int sn = 0; sn < 2; ++sn) {
                int ncol = wn + sn * 16 + lr;
                Vb[((size_t)bb * CD + o0 + orow) * ND + n0 + ncol] =
                    (f16)(acc[2][so][sn][r] + bv_);
            }
        }
}

// ============================================================================
// Kernel 2: flash attention, split-K (template KSN).
// 4 waves x 32 queries (QBLK=128).  KVB=32 keys/iter, double-buffered LDS,
// 2 blocks/CU.  SWAPPED QK^T: lane-local softmax.  Defer-max THR=5.
// XCD-pinned flat grid.  (Rolled main loop — unroll-2 measured slower.)
// ============================================================================
template<int KSN>
__global__ __launch_bounds__(256, 2)
void k_attn(const f16* __restrict__ Qt, const f16* __restrict__ Kt,
            const f16* __restrict__ Vb, f16* __restrict__ Op,
            float* __restrict__ ml)
{
    __shared__ f16 Ks[2][32 * 256];   // [buf][row][chunk16B ^ (row&7)]  2x16 KB
    __shared__ f16 Vs[2][256 * 32];   // [buf][c][chunk16B ^ ((c>>1)&3)] 2x16 KB
    __shared__ f16 Pl[4][32][40];     // per-wave P [q_local][m]

    const int t  = threadIdx.x;
    const int w  = t >> 6;           // 0..3
    const int l  = t & 63;
    const int lr = l & 15;
    const int lg = l >> 4;

    // ---- XCD-pinned decode ----
    const int bid = blockIdx.x;
    int bb, ks, qi;
    if constexpr (KSN == 8) {
        int xcd = bid & 7;
        bb = xcd & 1;
        ks = (xcd >> 1) | ((bid >> 8) << 2);
        qi = (bid >> 3) & 31;
    } else {   // KSN == 4
        bb = bid & 1;
        ks = (bid >> 1) & 3;
        qi = bid >> 3;
    }
    const int q0 = qi * 128 + w * 32;

    // Q fragments in registers: 2 q-subgroups x 8 k-chunks
    f16x8 qf[2][8];
#pragma unroll
    for (int qs = 0; qs < 2; ++qs)
#pragma unroll
        for (int kc = 0; kc < 8; ++kc)
            qf[qs][kc] = *(const f16x8*)(Qt + ((size_t)bb * ND + q0 + qs * 16 + lr) * CD + kc * 32 + lg * 8);

    f32x4 oacc[2][16] = {};
    float row_m[2] = { -3.0e38f, -3.0e38f };
    float row_l[2] = { 0.f, 0.f };

    const int kv0 = ks * (ND / KSN);
    const f16* ktb = Kt + (size_t)bb * ND * CD;
    const f16* vbb = Vb + (size_t)bb * CD * ND;

    // per-lane loop-invariant staging offsets (elements)
    int koff[4], voff[4];
#pragma unroll
    for (int j = 0; j < 4; ++j) {
        int v   = (w * 4 + j) * 64 + l;
        int row = v >> 5;
        int ch  = (v & 31) ^ (row & 7);
        koff[j] = row * CD + ch * 8;
        int c   = v >> 2;
        int u   = (v & 3) ^ ((c >> 1) & 3);
        voff[j] = c * ND + u * 8;
    }

    auto stage = [&](int m0, int bi) {
#pragma unroll
        for (int j = 0; j < 4; ++j)
            gl_lds16(ktb + (size_t)m0 * CD + koff[j], &Ks[bi][(w * 4 + j) * 512]);
#pragma unroll
        for (int j = 0; j < 4; ++j)
            gl_lds16(vbb + m0 + voff[j], &Vs[bi][(w * 4 + j) * 512]);
    };

    stage(kv0, 0);
    __syncthreads();    // drains vmcnt; tile 0 resident

    const int NIT = (ND / KSN) / KVB;
    for (int it = 0; it < NIT; ++it) {
        const int bi = it & 1;
        if (it + 1 < NIT) stage(kv0 + (it + 1) * KVB, bi ^ 1);

        // ---- scores S[m][q]: 2 m-subtiles x 2 q-subgroups ----
        f32x4 s[2][2] = {};
        __builtin_amdgcn_s_setprio(1);
#pragma unroll
        for (int kc = 0; kc < 8; ++kc) {
            int chs = ((kc * 4 + lg) ^ (lr & 7)) * 8;
            f16x8 k0 = *(const f16x8*)&Ks[bi][(lr) * 256 + chs];
            f16x8 k1 = *(const f16x8*)&Ks[bi][(16 + lr) * 256 + chs];
            s[0][0] = __builtin_amdgcn_mfma_f32_16x16x32_f16(k0, qf[0][kc], s[0][0], 0, 0, 0);
            s[1][0] = __builtin_amdgcn_mfma_f32_16x16x32_f16(k1, qf[0][kc], s[1][0], 0, 0, 0);
            s[0][1] = __builtin_amdgcn_mfma_f32_16x16x32_f16(k0, qf[1][kc], s[0][1], 0, 0, 0);
            s[1][1] = __builtin_amdgcn_mfma_f32_16x16x32_f16(k1, qf[1][kc], s[1][1], 0, 0, 0);
        }
        __builtin_amdgcn_s_setprio(0);

        // ---- lane-local online softmax per q-subgroup (defer-max THR=5) ----
#pragma unroll
        for (int qs = 0; qs < 2; ++qs) {
            float pm = fmaxf(
                fmaxf(fmaxf(s[0][qs][0], s[0][qs][1]), fmaxf(s[0][qs][2], s[0][qs][3])),
                fmaxf(fmaxf(s[1][qs][0], s[1][qs][1]), fmaxf(s[1][qs][2], s[1][qs][3])));
            pm = fmaxf(pm, __shfl_xor(pm, 16));
            pm = fmaxf(pm, __shfl_xor(pm, 32));
            bool need = (pm > row_m[qs] + 5.0f);   // defer small max growth
            float nm  = need ? pm : row_m[qs];
            float p0 = __expf(s[0][qs][0] - nm);
            float p1 = __expf(s[0][qs][1] - nm);
            float p2 = __expf(s[0][qs][2] - nm);
            float p3 = __expf(s[0][qs][3] - nm);
            float p4 = __expf(s[1][qs][0] - nm);
            float p5 = __expf(s[1][qs][1] - nm);
            float p6 = __expf(s[1][qs][2] - nm);
            float p7 = __expf(s[1][qs][3] - nm);
            float ps = ((p0 + p1) + (p2 + p3)) + ((p4 + p5) + (p6 + p7));
            ps += __shfl_xor(ps, 16);
            ps += __shfl_xor(ps, 32);
            if (__any(need)) {
                float sc = __expf(row_m[qs] - nm);   // == 1 for lanes w/o change
                row_l[qs] = row_l[qs] * sc + ps;
#pragma unroll
                for (int ct = 0; ct < 16; ++ct) {
                    oacc[qs][ct][0] *= sc; oacc[qs][ct][1] *= sc;
                    oacc[qs][ct][2] *= sc; oacc[qs][ct][3] *= sc;
                }
            } else {
                row_l[qs] += ps;
            }
            row_m[qs] = nm;
            f16x4 pk0 = { (f16)p0, (f16)p1, (f16)p2, (f16)p3 };
            f16x4 pk1 = { (f16)p4, (f16)p5, (f16)p6, (f16)p7 };
            *(f16x4*)&Pl[w][qs * 16 + lr][lg * 4]      = pk0;
            *(f16x4*)&Pl[w][qs * 16 + lr][16 + lg * 4] = pk1;
        }

        // ---- PV: O[c][q] += V[c][m] * P[m][q] ----
        f16x8 pf0 = *(const f16x8*)&Pl[w][lr][lg * 8];
        f16x8 pf1 = *(const f16x8*)&Pl[w][16 + lr][lg * 8];
        __builtin_amdgcn_s_setprio(1);
#pragma unroll
        for (int ct = 0; ct < 16; ++ct) {
            f16x8 vf = *(const f16x8*)&Vs[bi][(ct * 16 + lr) * 32 + ((lg ^ ((lr >> 1) & 3))) * 8];
            oacc[0][ct] = __builtin_amdgcn_mfma_f32_16x16x32_f16(vf, pf0, oacc[0][ct], 0, 0, 0);
            oacc[1][ct] = __builtin_amdgcn_mfma_f32_16x16x32_f16(vf, pf1, oacc[1][ct], 0, 0, 0);
        }
        __builtin_amdgcn_s_setprio(0);
        __syncthreads();   // drains stage(it+1); frees buffers for next iter
    }

    // ---- write unnormalized partial + (m,l) ----
#pragma unroll
    for (int qs = 0; qs < 2; ++qs)
#pragma unroll
        for (int ct = 0; ct < 16; ++ct)
#pragma unroll
            for (int r = 0; r < 4; ++r) {
                int cch = ct * 16 + lg * 4 + r;
                Op[(((size_t)ks * 2 + bb) * CD + cch) * ND + q0 + qs * 16 + lr] =
                    (f16)oacc[qs][ct][r];
            }
    if (lg == 0) {
#pragma unroll
        for (int qs = 0; qs < 2; ++qs) {
            int n = q0 + qs * 16 + lr;
            ml[((ks * 2 + bb) * 2 + 0) * ND + n] = row_m[qs];
            ml[((ks * 2 + bb) * 2 + 1) * ND + n] = row_l[qs];
        }
    }
}

// ============================================================================
// Kernel 2b-i: per-n combine weights  wq[ks][b][n] = exp(m-M)/L
// ============================================================================
template<int KSN>
__global__ __launch_bounds__(256)
void k_ml(const float* __restrict__ ml, float* __restrict__ wq)
{
    int i = blockIdx.x * 256 + threadIdx.x;   // i over B*ND
    int b = i / ND, n = i % ND;
    float m[KSN], lv[KSN];
#pragma unroll
    for (int ks = 0; ks < KSN; ++ks) {
        m[ks]  = ml[((ks * 2 + b) * 2 + 0) * ND + n];
        lv[ks] = ml[((ks * 2 + b) * 2 + 1) * ND + n];
    }
    float M = m[0];
#pragma unroll
    for (int ks = 1; ks < KSN; ++ks) M = fmaxf(M, m[ks]);
    float wgt[KSN], L = 0.f;
#pragma unroll
    for (int ks = 0; ks < KSN; ++ks) { wgt[ks] = __expf(m[ks] - M); L += wgt[ks] * lv[ks]; }
    float inv = 1.0f / L;
#pragma unroll
    for (int ks = 0; ks < KSN; ++ks)
        wq[(ks * 2 + b) * ND + n] = wgt[ks] * inv;
}

// ============================================================================
// Kernel 2b-ii: combine split-K partials -> Hb[b][c][n] f16 (vectorized)
// ============================================================================
template<int KSN>
__global__ __launch_bounds__(256)
void k_comb(const f16* __restrict__ Op, const float* __restrict__ wq,
            f16* __restrict__ Hb)
{
    size_t i = (size_t)blockIdx.x * 256 + threadIdx.x;   // one f16x8 each
    int n0 = (int)(i % (ND / 8)) * 8;
    int c  = (int)((i / (ND / 8)) % CD);
    int b  = (int)(i / ((size_t)CD * (ND / 8)));

    float acc[8] = {};
#pragma unroll
    for (int ks = 0; ks < KSN; ++ks) {
        f16x8 o = *(const f16x8*)(Op + (((size_t)ks * 2 + b) * CD + c) * ND + n0);
        const float* wp = wq + (ks * 2 + b) * ND + n0;
        float4 w0 = *(const float4*)wp;
        float4 w1 = *(const float4*)(wp + 4);
        acc[0] += w0.x * (float)o[0]; acc[1] += w0.y * (float)o[1];
        acc[2] += w0.z * (float)o[2]; acc[3] += w0.w * (float)o[3];
        acc[4] += w1.x * (float)o[4]; acc[5] += w1.y * (float)o[5];
        acc[6] += w1.z * (float)o[6]; acc[7] += w1.w * (float)o[7];
    }
    f16x8 h;
#pragma unroll
    for (int u = 0; u < 8; ++u) h[u] = (f16)acc[u];
    *(f16x8*)(Hb + ((size_t)b * CD + c) * ND + n0) = h;
}

// ============================================================================
// Kernel 3: output projection + residual.  Yh = f16(Wo@H + bo + x)
// Emits deterministic per-block GroupNorm partials (f32, pre-rounding).
// ============================================================================
__global__ __launch_bounds__(256)
void k_proj_o(const f16* __restrict__ Hb, const float* __restrict__ Wo,
              const float* __restrict__ bo, const float* __restrict__ x,
              f16* __restrict__ Yh, float* __restrict__ part)
{
    __shared__ f16 As[64][40];
    __shared__ f16 Bs[64][40];
    __shared__ float rs[4][2][2][2];   // [wave][so][lg>>1][{s,s2}]

    const int t  = threadIdx.x;
    const int n0 = blockIdx.x * 64;
    const int o0 = blockIdx.y * 64;
    const int bb = blockIdx.z;

    const int w  = t >> 6;
    const int l  = t & 63;
    const int lr = l & 15;
    const int lg = l >> 4;
    const int wo = (w >> 1) * 32;
    const int wn = (w & 1) * 32;

    const int sl = t & 63;
    const int k8 = (t >> 6) * 8;

    f32x4 acc[2][2] = {};

    for (int ck = 0; ck < CD; ck += 32) {
        __syncthreads();
        {
            const float* s = Wo + (size_t)(o0 + sl) * CD + ck + k8;
            f16x8 v;
#pragma unroll
            for (int u = 0; u < 8; ++u) v[u] = (f16)s[u];
            *(f16x8*)&As[sl][k8] = v;
        }
        {
            const f16* s = Hb + ((size_t)bb * CD + ck + k8) * ND + n0 + sl;
            f16x8 v;
#pragma unroll
            for (int u = 0; u < 8; ++u) v[u] = s[(size_t)u * ND];
            *(f16x8*)&Bs[sl][k8] = v;
        }
        __syncthreads();
        f16x8 a0 = *(const f16x8*)&As[wo + lr][lg * 8];
        f16x8 a1 = *(const f16x8*)&As[wo + 16 + lr][lg * 8];
        f16x8 b0 = *(const f16x8*)&Bs[wn + lr][lg * 8];
        f16x8 b1 = *(const f16x8*)&Bs[wn + 16 + lr][lg * 8];
        acc[0][0] = __builtin_amdgcn_mfma_f32_16x16x32_f16(a0, b0, acc[0][0], 0, 0, 0);
        acc[0][1] = __builtin_amdgcn_mfma_f32_16x16x32_f16(a0, b1, acc[0][1], 0, 0, 0);
        acc[1][0] = __builtin_amdgcn_mfma_f32_16x16x32_f16(a1, b0, acc[1][0], 0, 0, 0);
        acc[1][1] = __builtin_amdgcn_mfma_f32_16x16x32_f16(a1, b1, acc[1][1], 0, 0, 0);
    }

#pragma unroll
    for (int so = 0; so < 2; ++so) {
        float ls = 0.f, ls2 = 0.f;
#pragma unroll
        for (int r = 0; r < 4; ++r) {
            int orow  = wo + so * 16 + lg * 4 + r;
            float bv_ = bo[o0 + orow];
#pragma unroll
            for (int sn = 0; sn < 2; ++sn) {
                int ncol   = wn + sn * 16 + lr;
                size_t idx = ((size_t)bb * CD + o0 + orow) * ND + n0 + ncol;
                float v = acc[so][sn][r] + bv_ + x[idx];
                Yh[idx] = (f16)v;
                ls  += v;
                ls2 += v * v;
            }
        }
        // deterministic reduce over lanes sharing the same group
#pragma unroll
        for (int m = 1; m <= 16; m <<= 1) {
            ls  += __shfl_xor(ls, m);
            ls2 += __shfl_xor(ls2, m);
        }
        if ((l & 31) == 0) {
            rs[w][so][l >> 5][0] = ls;
            rs[w][so][l >> 5][1] = ls2;
        }
    }
    __syncthreads();
    if (t < 16) {
        int gl = t >> 1, st = t & 1;
        int a = gl >> 2, so = (gl >> 1) & 1, lh = gl & 1;
        float v = rs[2 * a][so][lh][st] + rs[2 * a + 1][so][lh][st];
        part[(((size_t)bb * GD + (o0 >> 3) + gl) * 64 + blockIdx.x) * 2 + st] = v;
    }
}

// ============================================================================
// Kernel 4: GroupNorm (from partials) + SiLU, single pass, f16 in / f32 out
// grid (32 groups, 2 batch, 4 n-quarters) = 256 blocks
// ============================================================================
__global__ __launch_bounds__(256)
void k_gn_silu(const f16* __restrict__ Yh, const float* __restrict__ part,
               const float* __restrict__ gamma, const float* __restrict__ beta,
               float* __restrict__ out)
{
    const int g  = blockIdx.x, b = blockIdx.y, nq = blockIdx.z;
    const int t  = threadIdx.x;

    __shared__ float mr[2];
    if (t < 64) {
        float s  = part[(((size_t)b * GD + g) * 64 + t) * 2 + 0];
        float s2 = part[(((size_t)b * GD + g) * 64 + t) * 2 + 1];
#pragma unroll
        for (int m = 1; m < 64; m <<= 1) {
            s  += __shfl_xor(s, m);
            s2 += __shfl_xor(s2, m);
        }
        if (t == 0) {
            float mean = s / 32768.f;
            float var  = s2 / 32768.f - mean * mean;
            mr[0] = mean;
            mr[1] = rsqrtf(var + 1e-5f);
        }
    }
    __syncthreads();
    const float mean = mr[0], rstd = mr[1];

    const size_t base = ((size_t)b * CD + g * 8) * ND;
    const f16x8* src = (const f16x8*)(Yh + base);

    // 8 channels x 1024 n per block = 1024 f16x8
    for (int i = t; i < 1024; i += 256) {
        int ch = i >> 7;                 // 128 f16x8 per channel-quarter
        int nn = i & 127;
        f16x8 v = src[ch * (ND / 8) + nq * 128 + nn];
        int c = g * 8 + ch;
        float ga = gamma[c], be = beta[c];
        float ob[8];
#pragma unroll
        for (int u = 0; u < 8; ++u) {
            float yn = ((float)v[u] - mean) * rstd * ga + be;
            float sg = 1.0f / (1.0f + __expf(-yn));
            ob[u] = yn * sg;
        }
        float* dp = out + base + (size_t)ch * ND + nq * 1024 + nn * 8;
        *(float4*)dp       = *(float4*)&ob[0];
        *(float4*)(dp + 4) = *(float4*)&ob[4];
    }
}

// ============================================================================
extern "C" void kernel_launch(void* const* d_in, const int* in_sizes, int n_in,
                              void* d_out, int out_size, void* d_ws, size_t ws_size,
                              hipStream_t stream)
{
    const float* x     = (const float*)d_in[0];
    const float* Wq    = (const float*)d_in[1];
    const float* bq    = (const float*)d_in[2];
    const float* Wk    = (const float*)d_in[3];
    const float* bk    = (const float*)d_in[4];
    const float* Wv    = (const float*)d_in[5];
    const float* bv    = (const float*)d_in[6];
    const float* Wo    = (const float*)d_in[7];
    const float* bo    = (const float*)d_in[8];
    const float* gamma = (const float*)d_in[9];
    const float* beta  = (const float*)d_in[10];

    char* ws = (char*)d_ws;
    f16* Qt = (f16*)(ws);                    //  0..4 MiB   [B][N][C]
    f16* Kt = (f16*)(ws + (4u << 20));       //  4..8 MiB   [B][N][C]
    f16* Vb = (f16*)(ws + (8u << 20));       //  8..12 MiB  [B][C][N]
    f16* Hb = (f16*)(ws + (12u << 20));      // 12..16 MiB  [B][C][N]
    f16* Op = (f16*)(ws + (16u << 20));      // 16.. MiB    [KSN][B][C][N]
    f16* Yh = (f16*)(ws + (16u << 20));      // reuses Op region after combine (8 MiB)

    const bool big = ws_size >= (50ull << 20);

    k_proj_qkv<<<dim3(64, 4, 2), 256, 0, stream>>>(x, Wq, bq, Wk, bk, Wv, bv, Qt, Kt, Vb);

    if (big) {
        constexpr int KSN = 8;
        float* ml   = (float*)(ws + (48u << 20));                 // 512 KB
        float* wq   = (float*)(ws + (48u << 20) + (768u << 10));  // 256 KB
        float* part = (float*)(ws + (49u << 20) + (512u << 10));  // 32 KB
        k_attn<KSN><<<dim3(32 * KSN * 2), 256, 0, stream>>>(Qt, Kt, Vb, Op, ml);
        k_ml<KSN><<<dim3((2 * ND) / 256), 256, 0, stream>>>(ml, wq);
        k_comb<KSN><<<dim3((2 * CD * ND / 8) / 256), 256, 0, stream>>>(Op, wq, Hb);
        k_proj_o<<<dim3(64, 4, 2), 256, 0, stream>>>(Hb, Wo, bo, x, Yh, part);
        k_gn_silu<<<dim3(GD, 2, 4), 256, 0, stream>>>(Yh, part, gamma, beta, (float*)d_out);
    } else {
        constexpr int KSN = 4;
        float* ml   = (float*)(ws + (32u << 20));                 // 256 KB
        float* wq   = (float*)(ws + (32u << 20) + (512u << 10));  // 128 KB
        float* part = (float*)(ws + (33u << 20));                 // 32 KB
        k_attn<KSN><<<dim3(32 * KSN * 2), 256, 0, stream>>>(Qt, Kt, Vb, Op, ml);
        k_ml<KSN><<<dim3((2 * ND) / 256), 256, 0, stream>>>(ml, wq);
        k_comb<KSN><<<dim3((2 * CD * ND / 8) / 256), 256, 0, stream>>>(Op, wq, Hb);
        k_proj_o<<<dim3(64, 4, 2), 256, 0, stream>>>(Hb, Wo, bo, x, Yh, part);
        k_gn_silu<<<dim3(GD, 2, 4), 256, 0, stream>>>(Yh, part, gamma, beta, (float*)d_out);
    }
}